// Round 4
// baseline (111.119 us; speedup 1.0000x reference)
//
#include <hip/hip_runtime.h>
#include <math.h>

// Renderer: occupancy-field ray marching + secant + shading.
// R10: 2 waves per ray, hidden-dim split. Grid was occupancy-capped at
//     16 waves/CU (4096 rays x 1 wave); HW allows 32/CU at VGPR<=64.
//     Block = 128 threads = 2 waves, 1 ray; wave w owns hidden units
//     [64w, 64w+64) (32 pair-slots). March partial logits exchanged in LDS
//     (1 barrier/batch, early-exit preserved); phase-3 partials exchanged
//     once; serial parts (geometry, l0 gate, search, secant) run redundantly
//     in both waves (identical data -> identical results, no sync).
//     Compositing split: wave0 scans A, hands TA+partial RGB via LDS,
//     wave1 scans B and writes. R9's manual prefetch reverted (regression:
//     +20 VGPR, -21 VALUBusy); Estrin softplus + logit-sign search kept.
// Carried: packed-f32 math, log2-domain softplus, pair-major LDS weights,
//     dfar==0 fast path, hoisted float2 weight loads.

namespace {

constexpr int H_    = 128;
constexpr int RS    = 128;   // RAY_STEPS
constexpr int NSEC  = 8;
constexpr int SOUT_ = 32;    // STEPS_OUT
constexpr int SIN_  = 64;    // STEPS_IN
constexpr int FULL_ = 96;
constexpr float EPSA   = 1e-6f;
constexpr float DELTA_ = 0.44626032029685964f; // max(2*exp(-1.5), 0.1)
constexpr float L2E    = 1.4426950408889634f;  // log2(e)
constexpr float LN2    = 0.6931471805599453f;

typedef __attribute__((ext_vector_type(2))) float f2;

__device__ __forceinline__ f2 s2(float v) { return f2{v, v}; }

// deg-6 poly for log2(1+e), e in [0,1], via t = 2e-1, max err ~1e-4. Estrin.
constexpr float PC0 =  0.5849625007211562f;
constexpr float PC1 =  0.4808983469629878f;
constexpr float PC2 = -0.0801497244938313f;
constexpr float PC3 =  0.0178110498875181f;
constexpr float PC4 = -0.0044527624718795f;
constexpr float PC5 =  0.0011873633258345f;
constexpr float PC6 = -0.0003298231460651f;

// packed log2-domain softplus: sp2(u) = max(u,0) + log2(1 + 2^-|u|)
__device__ __forceinline__ f2 sp2p(f2 u) {
    f2 e;
    e.x = __builtin_amdgcn_exp2f(-fabsf(u.x));
    e.y = __builtin_amdgcn_exp2f(-fabsf(u.y));
    f2 t  = e + e - 1.0f;
    f2 t2 = t * t;
    f2 t4 = t2 * t2;
    f2 A = __builtin_elementwise_fma(t, s2(PC1), s2(PC0));
    f2 B = __builtin_elementwise_fma(t, s2(PC3), s2(PC2));
    f2 C = __builtin_elementwise_fma(t, s2(PC5), s2(PC4));
    f2 E = __builtin_elementwise_fma(t2, B, A);
    f2 F = __builtin_elementwise_fma(t2, s2(PC6), C);
    f2 p = __builtin_elementwise_fma(t4, F, E);
    return __builtin_elementwise_max(u, s2(0.0f)) + p;
}

__device__ __forceinline__ float sigmoid_fast(float x) {
    return __builtin_amdgcn_rcpf(1.0f + __expf(-x));
}
__device__ __forceinline__ float sgnf(float p) {
    return (p > 0.0f) ? 1.0f : ((p < 0.0f) ? -1.0f : 0.0f);
}
__device__ __forceinline__ float secant_step(float f_l, float f_h, float d_l, float d_h) {
    float den = f_h - f_l;
    if (fabsf(den) > 1e-12f) return -f_l * (d_h - d_l) / den + d_l;
    return 0.5f * (d_l + d_h);
}
__device__ __forceinline__ float2 ld2(const float* p) {
    return *reinterpret_cast<const float2*>(p);
}

__device__ void inv4(const float* m, float* o) {
    float inv[16];
    inv[0]  =  m[5]*m[10]*m[15] - m[5]*m[11]*m[14] - m[9]*m[6]*m[15] + m[9]*m[7]*m[14] + m[13]*m[6]*m[11] - m[13]*m[7]*m[10];
    inv[4]  = -m[4]*m[10]*m[15] + m[4]*m[11]*m[14] + m[8]*m[6]*m[15] - m[8]*m[7]*m[14] - m[12]*m[6]*m[11] + m[12]*m[7]*m[10];
    inv[8]  =  m[4]*m[9]*m[15]  - m[4]*m[11]*m[13] - m[8]*m[5]*m[15] + m[8]*m[7]*m[13] + m[12]*m[5]*m[11] - m[12]*m[7]*m[9];
    inv[12] = -m[4]*m[9]*m[14]  + m[4]*m[10]*m[13] + m[8]*m[5]*m[14] - m[8]*m[6]*m[13] - m[12]*m[5]*m[10] + m[12]*m[6]*m[9];
    inv[1]  = -m[1]*m[10]*m[15] + m[1]*m[11]*m[14] + m[9]*m[2]*m[15] - m[9]*m[3]*m[14] - m[13]*m[2]*m[11] + m[13]*m[3]*m[10];
    inv[5]  =  m[0]*m[10]*m[15] - m[0]*m[11]*m[14] - m[8]*m[2]*m[15] + m[8]*m[3]*m[14] + m[12]*m[2]*m[11] - m[12]*m[3]*m[10];
    inv[9]  = -m[0]*m[9]*m[15]  + m[0]*m[11]*m[13] + m[8]*m[1]*m[15] - m[8]*m[3]*m[13] - m[12]*m[1]*m[11] + m[12]*m[3]*m[9];
    inv[13] =  m[0]*m[9]*m[14]  - m[0]*m[10]*m[13] - m[8]*m[1]*m[14] + m[8]*m[2]*m[13] + m[12]*m[1]*m[10] - m[12]*m[2]*m[9];
    inv[2]  =  m[1]*m[6]*m[15]  - m[1]*m[7]*m[14]  - m[5]*m[2]*m[15] + m[5]*m[3]*m[14] + m[13]*m[2]*m[7]  - m[13]*m[3]*m[6];
    inv[6]  = -m[0]*m[6]*m[15]  + m[0]*m[7]*m[14]  + m[4]*m[2]*m[15] - m[4]*m[3]*m[14] - m[12]*m[2]*m[7]  + m[12]*m[3]*m[6];
    inv[10] =  m[0]*m[5]*m[15]  - m[0]*m[7]*m[13]  - m[4]*m[1]*m[15] + m[4]*m[3]*m[13] + m[12]*m[1]*m[7]  - m[12]*m[3]*m[5];
    inv[14] = -m[0]*m[5]*m[14]  + m[0]*m[6]*m[13]  + m[4]*m[1]*m[14] - m[4]*m[2]*m[13] - m[12]*m[1]*m[6]  + m[12]*m[2]*m[5];
    inv[3]  = -m[1]*m[6]*m[11]  + m[1]*m[7]*m[10]  + m[5]*m[2]*m[11] - m[5]*m[3]*m[10] - m[9]*m[2]*m[7]   + m[9]*m[3]*m[6];
    inv[7]  =  m[0]*m[6]*m[11]  - m[0]*m[7]*m[10]  - m[4]*m[2]*m[11] + m[4]*m[3]*m[10] + m[8]*m[2]*m[7]   - m[8]*m[3]*m[6];
    inv[11] = -m[0]*m[5]*m[11]  + m[0]*m[7]*m[9]   + m[4]*m[1]*m[11] - m[4]*m[3]*m[9]  - m[8]*m[1]*m[7]   + m[8]*m[3]*m[5];
    inv[15] =  m[0]*m[5]*m[10]  - m[0]*m[6]*m[9]   - m[4]*m[1]*m[10] + m[4]*m[2]*m[9]  + m[8]*m[1]*m[6]   - m[8]*m[2]*m[5];
    float det = m[0]*inv[0] + m[1]*inv[4] + m[2]*inv[8] + m[3]*inv[12];
    float idet = 1.0f / det;
    for (int i = 0; i < 16; i++) o[i] = inv[i] * idet;
}

__global__ __launch_bounds__(128, 8) void render_k(
    const float* __restrict__ pixels,
    const float* __restrict__ Cm, const float* __restrict__ Wm, const float* __restrict__ Sm,
    const float* __restrict__ W1, const float* __restrict__ b1,
    const float* __restrict__ W2, const float* __restrict__ b2,
    const float* __restrict__ Wc1, const float* __restrict__ bc1,
    const float* __restrict__ Wc2, const float* __restrict__ bc2,
    float* __restrict__ out, int N)
{
    const int tid  = threadIdx.x;     // 0..127
    const int lane = tid & 63;
    const int wid  = tid >> 6;        // 0 or 1: hidden-half owner
    const int r    = blockIdx.x;      // one ray per block
    const int base = wid * 32;        // this wave's pair-slot range [base, base+32)

    // pair-major weight LDS: slot j2 holds hidden units 2*j2, 2*j2+1
    __shared__ float4 sP0[H_/2];      // {a,a', c,c'}       (occ, log2 domain)
    __shared__ float4 sP1[H_/2];      // {w,w', aC,aC'}     (w = w2*ln2)
    __shared__ float4 sP2[H_/2];      // {cC,cC', w0,w0'}
    __shared__ float4 sP3[H_/2];      // {w1,w1', w2,w2'}
    __shared__ f2     sW2[H_/2];      // {w,w'}  (occ-only marching loop)
    __shared__ float  sInv[3][16];    // iC, iW, iS
    __shared__ float  sT[16], sM[16];
    __shared__ float  sLgA[2][64];    // march batch-A partial logits
    __shared__ float  sLgB[2][64];    // march batch-B partial logits
    __shared__ float4 sEx0[2][64];    // phase-3 pass-0 partials {SO,A0,A1,A2}
    __shared__ float4 sEx1[2][32];    // phase-3 pass-1 partials
    __shared__ float  sCmp[4];        // compositing handoff {TA, sR, sG, sB}

    // ---- hoisted raw-weight loads ----
    const int u0 = 2 * lane;
    const float2 w1xv = ld2(W1 + u0);
    const float2 w1yv = ld2(W1 + H_ + u0);
    const float2 w1zv = ld2(W1 + 2*H_ + u0);
    const float2 b1v  = ld2(b1 + u0);
    const float2 w2v  = ld2(W2 + u0);
    float2 q0v{}, q1v{}, q2v{}, q3v{}, q4v{}, q5v{}, bc1v{}, wc2a{}, wc2b{}, wc2c{};
    if (wid == 0) {                   // color layer staged only by wave 0
        q0v  = ld2(Wc1 + u0);
        q1v  = ld2(Wc1 + H_ + u0);
        q2v  = ld2(Wc1 + 2*H_ + u0);
        q3v  = ld2(Wc1 + 3*H_ + u0);
        q4v  = ld2(Wc1 + 4*H_ + u0);
        q5v  = ld2(Wc1 + 5*H_ + u0);
        bc1v = ld2(bc1 + u0);
        wc2a = ld2(Wc2 + 3*u0);       // {w0[0], w1[0]}
        wc2b = ld2(Wc2 + 3*u0 + 2);   // {w2[0], w0[1]}
        wc2c = ld2(Wc2 + 3*u0 + 4);   // {w1[1], w2[1]}
    }
    const float b2v  = b2[0];
    const float bc20 = bc2[0], bc21 = bc2[1], bc22 = bc2[2];

    // ---- geometry: wave 0 computes the matrix chain ----
    if (wid == 0) {
        const float* mm = (lane == 0) ? Cm : ((lane == 1) ? Wm : Sm);
        float o[16];
        inv4(mm, o);                  // control-uniform; data-divergent
        if (lane < 3)
            for (int k = 0; k < 16; k++) sInv[lane][k] = o[k];
    }
    __syncthreads();
    if (wid == 0 && lane < 16) {      // T = iW @ iC
        int row = lane >> 2, col = lane & 3;
        float s = 0.0f;
        for (int k = 0; k < 4; k++) s += sInv[1][row*4 + k] * sInv[0][k*4 + col];
        sT[lane] = s;
    }
    __syncthreads();
    if (wid == 0 && lane < 16) {      // M = iS @ T
        int row = lane >> 2, col = lane & 3;
        float s = 0.0f;
        for (int k = 0; k < 4; k++) s += sInv[2][row*4 + k] * sT[k*4 + col];
        sM[lane] = s;
    }
    __syncthreads();

    // ---- per-ray geometry (redundant in both waves, identical) ----
    float cx, cy, cz, rx, ry, rz, dfar;
    int mint;
    {
        const float px_ = pixels[2*r], py_ = pixels[2*r + 1];
        float cam[3], dir[3];
        for (int i = 0; i < 3; i++) {
            cam[i] = sM[4*i + 3];
            float pw = sM[4*i + 0]*px_ + sM[4*i + 1]*py_ + sM[4*i + 2] + sM[4*i + 3];
            dir[i] = pw - cam[i];
        }
        float nrm = sqrtf(dir[0]*dir[0] + dir[1]*dir[1] + dir[2]*dir[2]);
        rx = dir[0]/nrm; ry = dir[1]/nrm; rz = dir[2]/nrm;
        cx = cam[0]; cy = cam[1]; cz = cam[2];
        float rcd = rx*cx + ry*cy + rz*cz;
        float cc  = cx*cx + cy*cy + cz*cz;
        float under = rcd*rcd - (cc - 1.0f);      // RADIUS = 1
        mint = under > 0.0f;
        float s = sqrtf(mint ? under : 1.0f);
        dfar = mint ? fmaxf(s - rcd, 0.0f) : 0.0f;
    }

    // ---- staging: occ reparam in both waves (secant needs it); LDS by wave0 ----
    float a2k[2], c2k[2], w2k[2];
    {
        a2k[0] = (w1xv.x*rx + w1yv.x*ry + w1zv.x*rz) * L2E;
        a2k[1] = (w1xv.y*rx + w1yv.y*ry + w1zv.y*rz) * L2E;
        c2k[0] = (w1xv.x*cx + w1yv.x*cy + w1zv.x*cz + b1v.x) * L2E;
        c2k[1] = (w1xv.y*cx + w1yv.y*cy + w1zv.y*cz + b1v.y) * L2E;
        w2k[0] = w2v.x * LN2;
        w2k[1] = w2v.y * LN2;
        if (wid == 0) {
            float aC0 = q0v.x*rx + q1v.x*ry + q2v.x*rz;
            float aC1 = q0v.y*rx + q1v.y*ry + q2v.y*rz;
            float cC0 = q0v.x*cx + q1v.x*cy + q2v.x*cz + bc1v.x - (q3v.x*rx + q4v.x*ry + q5v.x*rz);
            float cC1 = q0v.y*cx + q1v.y*cy + q2v.y*cz + bc1v.y - (q3v.y*rx + q4v.y*ry + q5v.y*rz);
            sP0[lane] = float4{a2k[0], a2k[1], c2k[0], c2k[1]};
            sP1[lane] = float4{w2k[0], w2k[1], aC0, aC1};
            sP2[lane] = float4{cC0, cC1, wc2a.x, wc2b.y};
            sP3[lane] = float4{wc2a.y, wc2c.x, wc2b.x, wc2c.y};
            sW2[lane] = f2{w2k[0], w2k[1]};
        }
    }
    __syncthreads();

    float alpha0 = 0.0f, r0c = 0.0f, g0c = 0.0f, b0c = 0.0f;   // wave0: samples 0..63
    float alpha1 = 0.0f, r1c = 0.0f, g1c = 0.0f, b1c = 0.0f;   // wave1: samples 64..95

    if (dfar == 0.0f) {
        // ---- fast path: all 96 samples at camera; both waves full-H redundant ----
        f2 sp = sp2p(f2{c2k[0], c2k[1]});
        float part = sp.x*w2k[0] + sp.y*w2k[1];
        float4 p2 = sP2[lane];
        float4 p3 = sP3[lane];
        f2 ff = __builtin_elementwise_max(f2{p2.x, p2.y}, s2(0.0f));
        float A0 = ff.x*p2.z + ff.y*p2.w;
        float A1 = ff.x*p3.x + ff.y*p3.y;
        float A2 = ff.x*p3.z + ff.y*p3.w;
#pragma unroll
        for (int off = 32; off; off >>= 1) {
            part += __shfl_xor(part, off, 64);
            A0   += __shfl_xor(A0,   off, 64);
            A1   += __shfl_xor(A1,   off, 64);
            A2   += __shfl_xor(A2,   off, 64);
        }
        alpha0 = sigmoid_fast(part + b2v);
        r0c = sigmoid_fast(A0 + bc20);
        g0c = sigmoid_fast(A1 + bc21);
        b0c = sigmoid_fast(A2 + bc22);
        alpha1 = alpha0; r1c = r0c; g1c = g0c; b1c = b0c;
    } else {
        const float inv127 = 1.0f / (RS - 1);

        // ---- phase 1a: logit at d=0 (redundant both waves, full H) ----
        float l0;
        {
            f2 sp = sp2p(f2{c2k[0], c2k[1]});
            float part = sp.x*w2k[0] + sp.y*w2k[1];
#pragma unroll
            for (int off = 32; off; off >>= 1) part += __shfl_xor(part, off, 64);
            l0 = part + b2v;
        }

        float d_i;
        if (l0 >= 0.0f) {
            d_i = 0.0f;               // march dead; background sampling
        } else {
            // partial occ logit over this wave's 32 pair-slots
            auto march32 = [&](float dsmp) -> float {
                const f2 dd = s2(dsmp);
                f2 acc = s2(0.0f);
#pragma unroll 4
                for (int j = 0; j < 32; ++j) {
                    float4 q0 = sP0[base + j];
                    f2 wv = sW2[base + j];
                    f2 u = __builtin_elementwise_fma(f2{q0.x, q0.y}, dd, f2{q0.z, q0.w});
                    acc = __builtin_elementwise_fma(sp2p(u), wv, acc);
                }
                return acc.x + acc.y;
            };

            // ---- batch A: steps 0..63, partials exchanged via LDS ----
            sLgA[wid][lane] = march32(dfar * ((float)lane * inv127));
            __syncthreads();
            float va = (sLgA[0][lane] + sLgA[1][lane]) + b2v;  // identical both waves
            float lan = __shfl_down(va, 1, 64);
            float ca = (lane < 63) ? sgnf(va * lan) * (float)(RS - lane) : 1.0f;
            float cmin = ca; int ind = lane;
#pragma unroll
            for (int off = 32; off; off >>= 1) {
                float c2 = __shfl_xor(cmin, off, 64);
                int   i2 = __shfl_xor(ind,  off, 64);
                if (c2 < cmin || (c2 == cmin && i2 < ind)) { cmin = c2; ind = i2; }
            }
            int crossed = cmin < 0.0f;            // block-uniform (identical data)
            float ll = 0.0f, lh = 0.0f;
            if (crossed) {
                ll = __shfl(va, ind, 64);
                lh = __shfl(va, ind + 1, 64);
            } else {
                // ---- batch B: steps 64..127 (only when half A is clean) ----
                sLgB[wid][lane] = march32(dfar * ((float)(lane + 64) * inv127));
                __syncthreads();
                float vb = (sLgB[0][lane] + sLgB[1][lane]) + b2v;
                float l63 = __shfl(va, 63, 64);
                float l64 = __shfl(vb, 0, 64);
                if (l63 * l64 < 0.0f) {           // boundary pair (63,64)
                    crossed = 1; ind = 63;
                    ll = l63; lh = l64;
                } else {
                    float lbn = __shfl_down(vb, 1, 64);
                    float cb = (lane < 63) ? sgnf(vb * lbn) * (float)(64 - lane) : 1.0f;
                    float cminb = cb; int indl = lane;
#pragma unroll
                    for (int off = 32; off; off >>= 1) {
                        float c2 = __shfl_xor(cminb, off, 64);
                        int   i2 = __shfl_xor(indl,  off, 64);
                        if (c2 < cminb || (c2 == cminb && i2 < indl)) { cminb = c2; indl = i2; }
                    }
                    if (cminb < 0.0f) {
                        crossed = 1; ind = 64 + indl;
                        ll = __shfl(vb, indl, 64);
                        lh = __shfl(vb, indl + 1, 64);
                    }
                }
            }

            const int msk = crossed && (ll < 0.0f) && mint;
            if (msk) {   // wave-uniform secant (redundant both waves, full H in regs)
                float f_l = sigmoid_fast(ll) - 0.5f;
                float f_h = sigmoid_fast(lh) - 0.5f;
                float d_l = dfar * ((float)ind * inv127);
                float d_h = dfar * ((float)(ind + 1) * inv127);
                float d_p = secant_step(f_l, f_h, d_l, d_h);
                for (int it = 0; it < NSEC; it++) {
                    f2 u2 = __builtin_elementwise_fma(f2{a2k[0], a2k[1]}, s2(d_p),
                                                      f2{c2k[0], c2k[1]});
                    f2 sp = sp2p(u2);
                    float part = sp.x*w2k[0] + sp.y*w2k[1];
#pragma unroll
                    for (int off = 32; off; off >>= 1) part += __shfl_xor(part, off, 64);
                    float fm = sigmoid_fast(part + b2v) - 0.5f;
                    bool low = fm < 0.0f;
                    d_l = low ? d_p : d_l;  f_l = low ? fm : f_l;
                    d_h = low ? d_h : d_p;  f_h = low ? f_h : fm;
                    d_p = secant_step(f_l, f_h, d_l, d_h);
                }
                d_i = d_p;
            } else {
                d_i = INFINITY;
            }
        }

        // ---- depth interval selection (redundant, identical) ----
        const int mask_zero = (d_i == 0.0f);
        const int mask_pred = isfinite(d_i);
        float dists = mask_pred ? d_i : 1.0f;
        if (mask_zero) dists = 0.0f;
        const int obj = mask_pred && !mask_zero;
        const float dnp = fmaxf(dists - DELTA_, 0.0f);
        const float dfp = fminf(dists + DELTA_, dfar);

        auto sample_d = [&](int s) -> float {
            if (obj) {
                if (s < SOUT_) return dnp * ((float)s * (1.0f / (SOUT_ - 1)));
                float u = (float)(s - SOUT_) * (1.0f / (SIN_ - 1));
                return dnp * (1.0f - u) + dfp * u;
            }
            return dfar * ((float)s * (1.0f / (FULL_ - 1)));
        };

        // ---- phase 3 partials over this wave's 32 pair-slots ----
        // pass 0: samples 0..63 (32 iters)
        {
            const f2 dd = s2(sample_d(lane));
            f2 SO = s2(0.0f), A0 = s2(0.0f), A1 = s2(0.0f), A2 = s2(0.0f);
#pragma unroll 4
            for (int j = 0; j < 32; ++j) {
                float4 q0 = sP0[base + j];
                float4 q1 = sP1[base + j];
                float4 q2 = sP2[base + j];
                float4 q3 = sP3[base + j];
                f2 u = __builtin_elementwise_fma(f2{q0.x, q0.y}, dd, f2{q0.z, q0.w});
                SO = __builtin_elementwise_fma(sp2p(u), f2{q1.x, q1.y}, SO);
                f2 f = __builtin_elementwise_max(
                           __builtin_elementwise_fma(f2{q1.z, q1.w}, dd, f2{q2.x, q2.y}),
                           s2(0.0f));
                A0 = __builtin_elementwise_fma(f, f2{q2.z, q2.w}, A0);
                A1 = __builtin_elementwise_fma(f, f2{q3.x, q3.y}, A1);
                A2 = __builtin_elementwise_fma(f, f2{q3.z, q3.w}, A2);
            }
            sEx0[wid][lane] = float4{SO.x + SO.y, A0.x + A0.y, A1.x + A1.y, A2.x + A2.y};
        }
        // pass 1: samples 64..95; 16 slots per half-wave, then xor-32 fold
        {
            const int s1 = 64 + (lane & 31);
            const int jb = base + (lane >> 5) * 16;
            const f2 dd = s2(sample_d(s1));
            f2 SO = s2(0.0f), A0 = s2(0.0f), A1 = s2(0.0f), A2 = s2(0.0f);
#pragma unroll 4
            for (int j = jb; j < jb + 16; ++j) {
                float4 q0 = sP0[j];
                float4 q1 = sP1[j];
                float4 q2 = sP2[j];
                float4 q3 = sP3[j];
                f2 u = __builtin_elementwise_fma(f2{q0.x, q0.y}, dd, f2{q0.z, q0.w});
                SO = __builtin_elementwise_fma(sp2p(u), f2{q1.x, q1.y}, SO);
                f2 f = __builtin_elementwise_max(
                           __builtin_elementwise_fma(f2{q1.z, q1.w}, dd, f2{q2.x, q2.y}),
                           s2(0.0f));
                A0 = __builtin_elementwise_fma(f, f2{q2.z, q2.w}, A0);
                A1 = __builtin_elementwise_fma(f, f2{q3.x, q3.y}, A1);
                A2 = __builtin_elementwise_fma(f, f2{q3.z, q3.w}, A2);
            }
            float SOs = SO.x + SO.y, A0s = A0.x + A0.y;
            float A1s = A1.x + A1.y, A2s = A2.x + A2.y;
            SOs += __shfl_xor(SOs, 32, 64);
            A0s += __shfl_xor(A0s, 32, 64);
            A1s += __shfl_xor(A1s, 32, 64);
            A2s += __shfl_xor(A2s, 32, 64);
            if (lane < 32) sEx1[wid][lane] = float4{SOs, A0s, A1s, A2s};
        }
        __syncthreads();

        // ---- finals: wave0 owns samples 0..63, wave1 owns 64..95 ----
        if (wid == 0) {
            float4 a = sEx0[0][lane], b = sEx0[1][lane];
            alpha0 = sigmoid_fast(a.x + b.x + b2v);
            r0c = sigmoid_fast(a.y + b.y + bc20);
            g0c = sigmoid_fast(a.z + b.z + bc21);
            b0c = sigmoid_fast(a.w + b.w + bc22);
        } else {
            float4 a = sEx1[0][lane & 31], b = sEx1[1][lane & 31];
            alpha1 = sigmoid_fast(a.x + b.x + b2v);
            r1c = sigmoid_fast(a.y + b.y + bc20);
            g1c = sigmoid_fast(a.z + b.z + bc21);
            b1c = sigmoid_fast(a.w + b.w + bc22);
        }
    }

    // ---- compositing split: wave0 scans A, wave1 scans B + writes ----
    if (wid == 0) {
        float p = 1.0f - alpha0 + EPSA;
#pragma unroll
        for (int off = 1; off < 64; off <<= 1) {
            float v = __shfl_up(p, off, 64);
            if (lane >= off) p *= v;
        }
        float TexA = __shfl_up(p, 1, 64);
        if (lane == 0) TexA = 1.0f;
        float TA = __shfl(p, 63, 64);
        float wA = alpha0 * TexA;
        float s0 = wA * r0c, s1 = wA * g0c, s2v = wA * b0c;
#pragma unroll
        for (int off = 32; off; off >>= 1) {
            s0  += __shfl_xor(s0,  off, 64);
            s1  += __shfl_xor(s1,  off, 64);
            s2v += __shfl_xor(s2v, off, 64);
        }
        if (lane == 0) {
            sCmp[0] = TA; sCmp[1] = s0; sCmp[2] = s1; sCmp[3] = s2v;
        }
    }
    __syncthreads();
    if (wid == 1) {
        const float TA = sCmp[0];
        float pb = (lane < 32) ? (1.0f - alpha1 + EPSA) : 1.0f;
#pragma unroll
        for (int off = 1; off < 32; off <<= 1) {
            float v = __shfl_up(pb, off, 64);
            if (lane >= off) pb *= v;
        }
        float TexB = __shfl_up(pb, 1, 64);
        if (lane == 0) TexB = 1.0f;
        float wB = (lane < 32) ? alpha1 * TexB * TA : 0.0f;
        float t0 = wB * r1c, t1 = wB * g1c, t2 = wB * b1c;
#pragma unroll
        for (int off = 32; off; off >>= 1) {
            t0 += __shfl_xor(t0, off, 64);
            t1 += __shfl_xor(t1, off, 64);
            t2 += __shfl_xor(t2, off, 64);
        }
        if (lane == 0) {
            out[3*r + 0] = sCmp[1] + t0;
            out[3*r + 1] = sCmp[2] + t1;
            out[3*r + 2] = sCmp[3] + t2;
        }
    }
}

} // namespace

extern "C" void kernel_launch(void* const* d_in, const int* in_sizes, int n_in,
                              void* d_out, int out_size, void* d_ws, size_t ws_size,
                              hipStream_t stream) {
    const float* pixels = (const float*)d_in[0];
    const float* Cm  = (const float*)d_in[1];
    const float* Wm  = (const float*)d_in[2];
    const float* Sm  = (const float*)d_in[3];
    const float* W1  = (const float*)d_in[4];
    const float* b1  = (const float*)d_in[5];
    const float* W2  = (const float*)d_in[6];
    const float* b2  = (const float*)d_in[7];
    const float* Wc1 = (const float*)d_in[8];
    const float* bc1 = (const float*)d_in[9];
    const float* Wc2 = (const float*)d_in[10];
    const float* bc2 = (const float*)d_in[11];
    float* out = (float*)d_out;

    const int N = in_sizes[0] / 2;   // pixels is (B=1, N, 2)
    hipLaunchKernelGGL(render_k, dim3(N), dim3(128), 0, stream,
                       pixels, Cm, Wm, Sm, W1, b1, W2, b2, Wc1, bc1, Wc2, bc2, out, N);
}

// Round 5
// 105.850 us; speedup vs baseline: 1.0498x; 1.0498x over previous
//
#include <hip/hip_runtime.h>
#include <math.h>

// Renderer: occupancy-field ray marching + secant + shading.
// R11: fix R10's spill storm. R10 proved the 2-wave/ray split doubles
//     occupancy (23.6->49%) but __launch_bounds__(128,8) + hoisted weight
//     loads (live across register-hungry inv4) forced VGPR=32 with scratch
//     traffic (FETCH 12.6MB / WRITE 7.8MB = spills) -> VALUBusy 47%.
//     Changes: (1) weight loads moved BELOW geometry (weights are
//     L2-resident; latency hidden by 32 waves/CU); (2) staging split:
//     wave0 stages occ tables (5 float2 loads), wave1 stages color tables
//     (14) -> peak live-set ~55 VGPR; (3) waves_per_eu pinned (8,8) so the
//     budget is exactly 64.
// Carried from R10: 2 waves/ray hidden-dim split, LDS partial-logit
//     exchange with early-exit march, redundant scalar phases, split
//     compositing. Carried from earlier: packed-f32 math, log2-domain
//     softplus (Estrin), pair-major LDS weights, dfar==0 fast path.

namespace {

constexpr int H_    = 128;
constexpr int RS    = 128;   // RAY_STEPS
constexpr int NSEC  = 8;
constexpr int SOUT_ = 32;    // STEPS_OUT
constexpr int SIN_  = 64;    // STEPS_IN
constexpr int FULL_ = 96;
constexpr float EPSA   = 1e-6f;
constexpr float DELTA_ = 0.44626032029685964f; // max(2*exp(-1.5), 0.1)
constexpr float L2E    = 1.4426950408889634f;  // log2(e)
constexpr float LN2    = 0.6931471805599453f;

typedef __attribute__((ext_vector_type(2))) float f2;

__device__ __forceinline__ f2 s2(float v) { return f2{v, v}; }

// deg-6 poly for log2(1+e), e in [0,1], via t = 2e-1, max err ~1e-4. Estrin.
constexpr float PC0 =  0.5849625007211562f;
constexpr float PC1 =  0.4808983469629878f;
constexpr float PC2 = -0.0801497244938313f;
constexpr float PC3 =  0.0178110498875181f;
constexpr float PC4 = -0.0044527624718795f;
constexpr float PC5 =  0.0011873633258345f;
constexpr float PC6 = -0.0003298231460651f;

// packed log2-domain softplus: sp2(u) = max(u,0) + log2(1 + 2^-|u|)
__device__ __forceinline__ f2 sp2p(f2 u) {
    f2 e;
    e.x = __builtin_amdgcn_exp2f(-fabsf(u.x));
    e.y = __builtin_amdgcn_exp2f(-fabsf(u.y));
    f2 t  = e + e - 1.0f;
    f2 t2 = t * t;
    f2 t4 = t2 * t2;
    f2 A = __builtin_elementwise_fma(t, s2(PC1), s2(PC0));
    f2 B = __builtin_elementwise_fma(t, s2(PC3), s2(PC2));
    f2 C = __builtin_elementwise_fma(t, s2(PC5), s2(PC4));
    f2 E = __builtin_elementwise_fma(t2, B, A);
    f2 F = __builtin_elementwise_fma(t2, s2(PC6), C);
    f2 p = __builtin_elementwise_fma(t4, F, E);
    return __builtin_elementwise_max(u, s2(0.0f)) + p;
}

__device__ __forceinline__ float sigmoid_fast(float x) {
    return __builtin_amdgcn_rcpf(1.0f + __expf(-x));
}
__device__ __forceinline__ float sgnf(float p) {
    return (p > 0.0f) ? 1.0f : ((p < 0.0f) ? -1.0f : 0.0f);
}
__device__ __forceinline__ float secant_step(float f_l, float f_h, float d_l, float d_h) {
    float den = f_h - f_l;
    if (fabsf(den) > 1e-12f) return -f_l * (d_h - d_l) / den + d_l;
    return 0.5f * (d_l + d_h);
}
__device__ __forceinline__ float2 ld2(const float* p) {
    return *reinterpret_cast<const float2*>(p);
}

__device__ void inv4(const float* m, float* o) {
    float inv[16];
    inv[0]  =  m[5]*m[10]*m[15] - m[5]*m[11]*m[14] - m[9]*m[6]*m[15] + m[9]*m[7]*m[14] + m[13]*m[6]*m[11] - m[13]*m[7]*m[10];
    inv[4]  = -m[4]*m[10]*m[15] + m[4]*m[11]*m[14] + m[8]*m[6]*m[15] - m[8]*m[7]*m[14] - m[12]*m[6]*m[11] + m[12]*m[7]*m[10];
    inv[8]  =  m[4]*m[9]*m[15]  - m[4]*m[11]*m[13] - m[8]*m[5]*m[15] + m[8]*m[7]*m[13] + m[12]*m[5]*m[11] - m[12]*m[7]*m[9];
    inv[12] = -m[4]*m[9]*m[14]  + m[4]*m[10]*m[13] + m[8]*m[5]*m[14] - m[8]*m[6]*m[13] - m[12]*m[5]*m[10] + m[12]*m[6]*m[9];
    inv[1]  = -m[1]*m[10]*m[15] + m[1]*m[11]*m[14] + m[9]*m[2]*m[15] - m[9]*m[3]*m[14] - m[13]*m[2]*m[11] + m[13]*m[3]*m[10];
    inv[5]  =  m[0]*m[10]*m[15] - m[0]*m[11]*m[14] - m[8]*m[2]*m[15] + m[8]*m[3]*m[14] + m[12]*m[2]*m[11] - m[12]*m[3]*m[10];
    inv[9]  = -m[0]*m[9]*m[15]  + m[0]*m[11]*m[13] + m[8]*m[1]*m[15] - m[8]*m[3]*m[13] - m[12]*m[1]*m[11] + m[12]*m[3]*m[9];
    inv[13] =  m[0]*m[9]*m[14]  - m[0]*m[10]*m[13] - m[8]*m[1]*m[14] + m[8]*m[2]*m[13] + m[12]*m[1]*m[10] - m[12]*m[2]*m[9];
    inv[2]  =  m[1]*m[6]*m[15]  - m[1]*m[7]*m[14]  - m[5]*m[2]*m[15] + m[5]*m[3]*m[14] + m[13]*m[2]*m[7]  - m[13]*m[3]*m[6];
    inv[6]  = -m[0]*m[6]*m[15]  + m[0]*m[7]*m[14]  + m[4]*m[2]*m[15] - m[4]*m[3]*m[14] - m[12]*m[2]*m[7]  + m[12]*m[3]*m[6];
    inv[10] =  m[0]*m[5]*m[15]  - m[0]*m[7]*m[13]  - m[4]*m[1]*m[15] + m[4]*m[3]*m[13] + m[12]*m[1]*m[7]  - m[12]*m[3]*m[5];
    inv[14] = -m[0]*m[5]*m[14]  + m[0]*m[6]*m[13]  + m[4]*m[1]*m[14] - m[4]*m[2]*m[13] - m[12]*m[1]*m[6]  + m[12]*m[2]*m[5];
    inv[3]  = -m[1]*m[6]*m[11]  + m[1]*m[7]*m[10]  + m[5]*m[2]*m[11] - m[5]*m[3]*m[10] - m[9]*m[2]*m[7]   + m[9]*m[3]*m[6];
    inv[7]  =  m[0]*m[6]*m[11]  - m[0]*m[7]*m[10]  - m[4]*m[2]*m[11] + m[4]*m[3]*m[10] + m[8]*m[2]*m[7]   - m[8]*m[3]*m[6];
    inv[11] = -m[0]*m[5]*m[11]  + m[0]*m[7]*m[9]   + m[4]*m[1]*m[11] - m[4]*m[3]*m[9]  - m[8]*m[1]*m[7]   + m[8]*m[3]*m[5];
    inv[15] =  m[0]*m[5]*m[10]  - m[0]*m[6]*m[9]   - m[4]*m[1]*m[10] + m[4]*m[2]*m[9]  + m[8]*m[1]*m[6]   - m[8]*m[2]*m[5];
    float det = m[0]*inv[0] + m[1]*inv[4] + m[2]*inv[8] + m[3]*inv[12];
    float idet = 1.0f / det;
    for (int i = 0; i < 16; i++) o[i] = inv[i] * idet;
}

__global__ __launch_bounds__(128)
__attribute__((amdgpu_waves_per_eu(8, 8)))
void render_k(
    const float* __restrict__ pixels,
    const float* __restrict__ Cm, const float* __restrict__ Wm, const float* __restrict__ Sm,
    const float* __restrict__ W1, const float* __restrict__ b1,
    const float* __restrict__ W2, const float* __restrict__ b2,
    const float* __restrict__ Wc1, const float* __restrict__ bc1,
    const float* __restrict__ Wc2, const float* __restrict__ bc2,
    float* __restrict__ out, int N)
{
    const int tid  = threadIdx.x;     // 0..127
    const int lane = tid & 63;
    const int wid  = tid >> 6;        // 0 or 1: hidden-half owner
    const int r    = blockIdx.x;      // one ray per block
    const int base = wid * 32;        // this wave's pair-slot range [base, base+32)

    // pair-major weight LDS: slot j2 holds hidden units 2*j2, 2*j2+1
    __shared__ float4 sP0[H_/2];      // {a,a', c,c'}       (occ, log2 domain)
    __shared__ float4 sP1[H_/2];      // {w,w', aC,aC'}     (w = w2*ln2)
    __shared__ float4 sP2[H_/2];      // {cC,cC', w0,w0'}
    __shared__ float4 sP3[H_/2];      // {w1,w1', w2,w2'}
    __shared__ f2     sW2[H_/2];      // {w,w'}  (occ-only marching loop)
    __shared__ float  sInv[3][16];    // iC, iW, iS
    __shared__ float  sT[16], sM[16];
    __shared__ float  sLgA[2][64];    // march batch-A partial logits
    __shared__ float  sLgB[2][64];    // march batch-B partial logits
    __shared__ float4 sEx0[2][64];    // phase-3 pass-0 partials {SO,A0,A1,A2}
    __shared__ float4 sEx1[2][32];    // phase-3 pass-1 partials
    __shared__ float  sCmp[4];        // compositing handoff {TA, sR, sG, sB}

    // ---- geometry: wave 0 computes the matrix chain (no loads hoisted above) ----
    if (wid == 0) {
        const float* mm = (lane == 0) ? Cm : ((lane == 1) ? Wm : Sm);
        float o[16];
        inv4(mm, o);                  // control-uniform; data-divergent
        if (lane < 3)
            for (int k = 0; k < 16; k++) sInv[lane][k] = o[k];
    }
    __syncthreads();
    if (wid == 0 && lane < 16) {      // T = iW @ iC
        int row = lane >> 2, col = lane & 3;
        float s = 0.0f;
        for (int k = 0; k < 4; k++) s += sInv[1][row*4 + k] * sInv[0][k*4 + col];
        sT[lane] = s;
    }
    __syncthreads();
    if (wid == 0 && lane < 16) {      // M = iS @ T
        int row = lane >> 2, col = lane & 3;
        float s = 0.0f;
        for (int k = 0; k < 4; k++) s += sInv[2][row*4 + k] * sT[k*4 + col];
        sM[lane] = s;
    }
    __syncthreads();

    // ---- per-ray geometry (redundant in both waves, identical) ----
    float cx, cy, cz, rx, ry, rz, dfar;
    int mint;
    {
        const float px_ = pixels[2*r], py_ = pixels[2*r + 1];
        float cam[3], dir[3];
        for (int i = 0; i < 3; i++) {
            cam[i] = sM[4*i + 3];
            float pw = sM[4*i + 0]*px_ + sM[4*i + 1]*py_ + sM[4*i + 2] + sM[4*i + 3];
            dir[i] = pw - cam[i];
        }
        float nrm = sqrtf(dir[0]*dir[0] + dir[1]*dir[1] + dir[2]*dir[2]);
        rx = dir[0]/nrm; ry = dir[1]/nrm; rz = dir[2]/nrm;
        cx = cam[0]; cy = cam[1]; cz = cam[2];
        float rcd = rx*cx + ry*cy + rz*cz;
        float cc  = cx*cx + cy*cy + cz*cz;
        float under = rcd*rcd - (cc - 1.0f);      // RADIUS = 1
        mint = under > 0.0f;
        float s = sqrtf(mint ? under : 1.0f);
        dfar = mint ? fmaxf(s - rcd, 0.0f) : 0.0f;
    }

    // ---- staging (after geometry; split: wave0 = occ LDS, wave1 = color LDS) ----
    const int u0 = 2 * lane;
    float a2k[2], c2k[2], w2k[2];     // both waves need these in regs
    {
        const float2 w1xv = ld2(W1 + u0);
        const float2 w1yv = ld2(W1 + H_ + u0);
        const float2 w1zv = ld2(W1 + 2*H_ + u0);
        const float2 b1v  = ld2(b1 + u0);
        const float2 w2v  = ld2(W2 + u0);
        a2k[0] = (w1xv.x*rx + w1yv.x*ry + w1zv.x*rz) * L2E;
        a2k[1] = (w1xv.y*rx + w1yv.y*ry + w1zv.y*rz) * L2E;
        c2k[0] = (w1xv.x*cx + w1yv.x*cy + w1zv.x*cz + b1v.x) * L2E;
        c2k[1] = (w1xv.y*cx + w1yv.y*cy + w1zv.y*cz + b1v.y) * L2E;
        w2k[0] = w2v.x * LN2;
        w2k[1] = w2v.y * LN2;
        if (wid == 0) {
            sP0[lane] = float4{a2k[0], a2k[1], c2k[0], c2k[1]};
            sW2[lane] = f2{w2k[0], w2k[1]};
        } else {
            const float2 q0v  = ld2(Wc1 + u0);
            const float2 q1v  = ld2(Wc1 + H_ + u0);
            const float2 q2v  = ld2(Wc1 + 2*H_ + u0);
            float aC0 = q0v.x*rx + q1v.x*ry + q2v.x*rz;
            float aC1 = q0v.y*rx + q1v.y*ry + q2v.y*rz;
            float cB0 = q0v.x*cx + q1v.x*cy + q2v.x*cz;
            float cB1 = q0v.y*cx + q1v.y*cy + q2v.y*cz;
            sP1[lane] = float4{w2k[0], w2k[1], aC0, aC1};
            const float2 q3v  = ld2(Wc1 + 3*H_ + u0);
            const float2 q4v  = ld2(Wc1 + 4*H_ + u0);
            const float2 q5v  = ld2(Wc1 + 5*H_ + u0);
            const float2 bc1v = ld2(bc1 + u0);
            float cC0 = cB0 + bc1v.x - (q3v.x*rx + q4v.x*ry + q5v.x*rz);
            float cC1 = cB1 + bc1v.y - (q3v.y*rx + q4v.y*ry + q5v.y*rz);
            const float2 wc2a = ld2(Wc2 + 3*u0);      // {w0[0], w1[0]}
            const float2 wc2b = ld2(Wc2 + 3*u0 + 2);  // {w2[0], w0[1]}
            const float2 wc2c = ld2(Wc2 + 3*u0 + 4);  // {w1[1], w2[1]}
            sP2[lane] = float4{cC0, cC1, wc2a.x, wc2b.y};
            sP3[lane] = float4{wc2a.y, wc2c.x, wc2b.x, wc2c.y};
        }
    }
    const float b2v  = b2[0];
    const float bc20 = bc2[0], bc21 = bc2[1], bc22 = bc2[2];
    __syncthreads();

    float alpha0 = 0.0f, r0c = 0.0f, g0c = 0.0f, b0c = 0.0f;   // wave0: samples 0..63
    float alpha1 = 0.0f, r1c = 0.0f, g1c = 0.0f, b1c = 0.0f;   // wave1: samples 64..95

    if (dfar == 0.0f) {
        // ---- fast path: all 96 samples at camera; both waves full-H redundant ----
        f2 sp = sp2p(f2{c2k[0], c2k[1]});
        float part = sp.x*w2k[0] + sp.y*w2k[1];
        float4 p2 = sP2[lane];
        float4 p3 = sP3[lane];
        f2 ff = __builtin_elementwise_max(f2{p2.x, p2.y}, s2(0.0f));
        float A0 = ff.x*p2.z + ff.y*p2.w;
        float A1 = ff.x*p3.x + ff.y*p3.y;
        float A2 = ff.x*p3.z + ff.y*p3.w;
#pragma unroll
        for (int off = 32; off; off >>= 1) {
            part += __shfl_xor(part, off, 64);
            A0   += __shfl_xor(A0,   off, 64);
            A1   += __shfl_xor(A1,   off, 64);
            A2   += __shfl_xor(A2,   off, 64);
        }
        alpha0 = sigmoid_fast(part + b2v);
        r0c = sigmoid_fast(A0 + bc20);
        g0c = sigmoid_fast(A1 + bc21);
        b0c = sigmoid_fast(A2 + bc22);
        alpha1 = alpha0; r1c = r0c; g1c = g0c; b1c = b0c;
    } else {
        const float inv127 = 1.0f / (RS - 1);

        // ---- phase 1a: logit at d=0 (redundant both waves, full H) ----
        float l0;
        {
            f2 sp = sp2p(f2{c2k[0], c2k[1]});
            float part = sp.x*w2k[0] + sp.y*w2k[1];
#pragma unroll
            for (int off = 32; off; off >>= 1) part += __shfl_xor(part, off, 64);
            l0 = part + b2v;
        }

        float d_i;
        if (l0 >= 0.0f) {
            d_i = 0.0f;               // march dead; background sampling
        } else {
            // partial occ logit over this wave's 32 pair-slots
            auto march32 = [&](float dsmp) -> float {
                const f2 dd = s2(dsmp);
                f2 acc = s2(0.0f);
#pragma unroll 4
                for (int j = 0; j < 32; ++j) {
                    float4 q0 = sP0[base + j];
                    f2 wv = sW2[base + j];
                    f2 u = __builtin_elementwise_fma(f2{q0.x, q0.y}, dd, f2{q0.z, q0.w});
                    acc = __builtin_elementwise_fma(sp2p(u), wv, acc);
                }
                return acc.x + acc.y;
            };

            // ---- batch A: steps 0..63, partials exchanged via LDS ----
            sLgA[wid][lane] = march32(dfar * ((float)lane * inv127));
            __syncthreads();
            float va = (sLgA[0][lane] + sLgA[1][lane]) + b2v;  // identical both waves
            float lan = __shfl_down(va, 1, 64);
            float ca = (lane < 63) ? sgnf(va * lan) * (float)(RS - lane) : 1.0f;
            float cmin = ca; int ind = lane;
#pragma unroll
            for (int off = 32; off; off >>= 1) {
                float c2 = __shfl_xor(cmin, off, 64);
                int   i2 = __shfl_xor(ind,  off, 64);
                if (c2 < cmin || (c2 == cmin && i2 < ind)) { cmin = c2; ind = i2; }
            }
            int crossed = cmin < 0.0f;            // block-uniform (identical data)
            float ll = 0.0f, lh = 0.0f;
            if (crossed) {
                ll = __shfl(va, ind, 64);
                lh = __shfl(va, ind + 1, 64);
            } else {
                // ---- batch B: steps 64..127 (only when half A is clean) ----
                sLgB[wid][lane] = march32(dfar * ((float)(lane + 64) * inv127));
                __syncthreads();
                float vb = (sLgB[0][lane] + sLgB[1][lane]) + b2v;
                float l63 = __shfl(va, 63, 64);
                float l64 = __shfl(vb, 0, 64);
                if (l63 * l64 < 0.0f) {           // boundary pair (63,64)
                    crossed = 1; ind = 63;
                    ll = l63; lh = l64;
                } else {
                    float lbn = __shfl_down(vb, 1, 64);
                    float cb = (lane < 63) ? sgnf(vb * lbn) * (float)(64 - lane) : 1.0f;
                    float cminb = cb; int indl = lane;
#pragma unroll
                    for (int off = 32; off; off >>= 1) {
                        float c2 = __shfl_xor(cminb, off, 64);
                        int   i2 = __shfl_xor(indl,  off, 64);
                        if (c2 < cminb || (c2 == cminb && i2 < indl)) { cminb = c2; indl = i2; }
                    }
                    if (cminb < 0.0f) {
                        crossed = 1; ind = 64 + indl;
                        ll = __shfl(vb, indl, 64);
                        lh = __shfl(vb, indl + 1, 64);
                    }
                }
            }

            const int msk = crossed && (ll < 0.0f) && mint;
            if (msk) {   // wave-uniform secant (redundant both waves, full H in regs)
                float f_l = sigmoid_fast(ll) - 0.5f;
                float f_h = sigmoid_fast(lh) - 0.5f;
                float d_l = dfar * ((float)ind * inv127);
                float d_h = dfar * ((float)(ind + 1) * inv127);
                float d_p = secant_step(f_l, f_h, d_l, d_h);
                for (int it = 0; it < NSEC; it++) {
                    f2 u2 = __builtin_elementwise_fma(f2{a2k[0], a2k[1]}, s2(d_p),
                                                      f2{c2k[0], c2k[1]});
                    f2 sp = sp2p(u2);
                    float part = sp.x*w2k[0] + sp.y*w2k[1];
#pragma unroll
                    for (int off = 32; off; off >>= 1) part += __shfl_xor(part, off, 64);
                    float fm = sigmoid_fast(part + b2v) - 0.5f;
                    bool low = fm < 0.0f;
                    d_l = low ? d_p : d_l;  f_l = low ? fm : f_l;
                    d_h = low ? d_h : d_p;  f_h = low ? f_h : fm;
                    d_p = secant_step(f_l, f_h, d_l, d_h);
                }
                d_i = d_p;
            } else {
                d_i = INFINITY;
            }
        }

        // ---- depth interval selection (redundant, identical) ----
        const int mask_zero = (d_i == 0.0f);
        const int mask_pred = isfinite(d_i);
        float dists = mask_pred ? d_i : 1.0f;
        if (mask_zero) dists = 0.0f;
        const int obj = mask_pred && !mask_zero;
        const float dnp = fmaxf(dists - DELTA_, 0.0f);
        const float dfp = fminf(dists + DELTA_, dfar);

        auto sample_d = [&](int s) -> float {
            if (obj) {
                if (s < SOUT_) return dnp * ((float)s * (1.0f / (SOUT_ - 1)));
                float u = (float)(s - SOUT_) * (1.0f / (SIN_ - 1));
                return dnp * (1.0f - u) + dfp * u;
            }
            return dfar * ((float)s * (1.0f / (FULL_ - 1)));
        };

        // ---- phase 3 partials over this wave's 32 pair-slots ----
        // pass 0: samples 0..63 (32 iters)
        {
            const f2 dd = s2(sample_d(lane));
            f2 SO = s2(0.0f), A0 = s2(0.0f), A1 = s2(0.0f), A2 = s2(0.0f);
#pragma unroll 4
            for (int j = 0; j < 32; ++j) {
                float4 q0 = sP0[base + j];
                float4 q1 = sP1[base + j];
                float4 q2 = sP2[base + j];
                float4 q3 = sP3[base + j];
                f2 u = __builtin_elementwise_fma(f2{q0.x, q0.y}, dd, f2{q0.z, q0.w});
                SO = __builtin_elementwise_fma(sp2p(u), f2{q1.x, q1.y}, SO);
                f2 f = __builtin_elementwise_max(
                           __builtin_elementwise_fma(f2{q1.z, q1.w}, dd, f2{q2.x, q2.y}),
                           s2(0.0f));
                A0 = __builtin_elementwise_fma(f, f2{q2.z, q2.w}, A0);
                A1 = __builtin_elementwise_fma(f, f2{q3.x, q3.y}, A1);
                A2 = __builtin_elementwise_fma(f, f2{q3.z, q3.w}, A2);
            }
            sEx0[wid][lane] = float4{SO.x + SO.y, A0.x + A0.y, A1.x + A1.y, A2.x + A2.y};
        }
        // pass 1: samples 64..95; 16 slots per half-wave, then xor-32 fold
        {
            const int s1 = 64 + (lane & 31);
            const int jb = base + (lane >> 5) * 16;
            const f2 dd = s2(sample_d(s1));
            f2 SO = s2(0.0f), A0 = s2(0.0f), A1 = s2(0.0f), A2 = s2(0.0f);
#pragma unroll 4
            for (int j = jb; j < jb + 16; ++j) {
                float4 q0 = sP0[j];
                float4 q1 = sP1[j];
                float4 q2 = sP2[j];
                float4 q3 = sP3[j];
                f2 u = __builtin_elementwise_fma(f2{q0.x, q0.y}, dd, f2{q0.z, q0.w});
                SO = __builtin_elementwise_fma(sp2p(u), f2{q1.x, q1.y}, SO);
                f2 f = __builtin_elementwise_max(
                           __builtin_elementwise_fma(f2{q1.z, q1.w}, dd, f2{q2.x, q2.y}),
                           s2(0.0f));
                A0 = __builtin_elementwise_fma(f, f2{q2.z, q2.w}, A0);
                A1 = __builtin_elementwise_fma(f, f2{q3.x, q3.y}, A1);
                A2 = __builtin_elementwise_fma(f, f2{q3.z, q3.w}, A2);
            }
            float SOs = SO.x + SO.y, A0s = A0.x + A0.y;
            float A1s = A1.x + A1.y, A2s = A2.x + A2.y;
            SOs += __shfl_xor(SOs, 32, 64);
            A0s += __shfl_xor(A0s, 32, 64);
            A1s += __shfl_xor(A1s, 32, 64);
            A2s += __shfl_xor(A2s, 32, 64);
            if (lane < 32) sEx1[wid][lane] = float4{SOs, A0s, A1s, A2s};
        }
        __syncthreads();

        // ---- finals: wave0 owns samples 0..63, wave1 owns 64..95 ----
        if (wid == 0) {
            float4 a = sEx0[0][lane], b = sEx0[1][lane];
            alpha0 = sigmoid_fast(a.x + b.x + b2v);
            r0c = sigmoid_fast(a.y + b.y + bc20);
            g0c = sigmoid_fast(a.z + b.z + bc21);
            b0c = sigmoid_fast(a.w + b.w + bc22);
        } else {
            float4 a = sEx1[0][lane & 31], b = sEx1[1][lane & 31];
            alpha1 = sigmoid_fast(a.x + b.x + b2v);
            r1c = sigmoid_fast(a.y + b.y + bc20);
            g1c = sigmoid_fast(a.z + b.z + bc21);
            b1c = sigmoid_fast(a.w + b.w + bc22);
        }
    }

    // ---- compositing split: wave0 scans A, wave1 scans B + writes ----
    if (wid == 0) {
        float p = 1.0f - alpha0 + EPSA;
#pragma unroll
        for (int off = 1; off < 64; off <<= 1) {
            float v = __shfl_up(p, off, 64);
            if (lane >= off) p *= v;
        }
        float TexA = __shfl_up(p, 1, 64);
        if (lane == 0) TexA = 1.0f;
        float TA = __shfl(p, 63, 64);
        float wA = alpha0 * TexA;
        float s0 = wA * r0c, s1 = wA * g0c, s2v = wA * b0c;
#pragma unroll
        for (int off = 32; off; off >>= 1) {
            s0  += __shfl_xor(s0,  off, 64);
            s1  += __shfl_xor(s1,  off, 64);
            s2v += __shfl_xor(s2v, off, 64);
        }
        if (lane == 0) {
            sCmp[0] = TA; sCmp[1] = s0; sCmp[2] = s1; sCmp[3] = s2v;
        }
    }
    __syncthreads();
    if (wid == 1) {
        const float TA = sCmp[0];
        float pb = (lane < 32) ? (1.0f - alpha1 + EPSA) : 1.0f;
#pragma unroll
        for (int off = 1; off < 32; off <<= 1) {
            float v = __shfl_up(pb, off, 64);
            if (lane >= off) pb *= v;
        }
        float TexB = __shfl_up(pb, 1, 64);
        if (lane == 0) TexB = 1.0f;
        float wB = (lane < 32) ? alpha1 * TexB * TA : 0.0f;
        float t0 = wB * r1c, t1 = wB * g1c, t2 = wB * b1c;
#pragma unroll
        for (int off = 32; off; off >>= 1) {
            t0 += __shfl_xor(t0, off, 64);
            t1 += __shfl_xor(t1, off, 64);
            t2 += __shfl_xor(t2, off, 64);
        }
        if (lane == 0) {
            out[3*r + 0] = sCmp[1] + t0;
            out[3*r + 1] = sCmp[2] + t1;
            out[3*r + 2] = sCmp[3] + t2;
        }
    }
}

} // namespace

extern "C" void kernel_launch(void* const* d_in, const int* in_sizes, int n_in,
                              void* d_out, int out_size, void* d_ws, size_t ws_size,
                              hipStream_t stream) {
    const float* pixels = (const float*)d_in[0];
    const float* Cm  = (const float*)d_in[1];
    const float* Wm  = (const float*)d_in[2];
    const float* Sm  = (const float*)d_in[3];
    const float* W1  = (const float*)d_in[4];
    const float* b1  = (const float*)d_in[5];
    const float* W2  = (const float*)d_in[6];
    const float* b2  = (const float*)d_in[7];
    const float* Wc1 = (const float*)d_in[8];
    const float* bc1 = (const float*)d_in[9];
    const float* Wc2 = (const float*)d_in[10];
    const float* bc2 = (const float*)d_in[11];
    float* out = (float*)d_out;

    const int N = in_sizes[0] / 2;   // pixels is (B=1, N, 2)
    hipLaunchKernelGGL(render_k, dim3(N), dim3(128), 0, stream,
                       pixels, Cm, Wm, Sm, W1, b1, W2, b2, Wc1, bc1, Wc2, bc2, out, N);
}

// Round 6
// 104.601 us; speedup vs baseline: 1.0623x; 1.0119x over previous
//
#include <hip/hip_runtime.h>
#include <math.h>

// Renderer: occupancy-field ray marching + secant + shading.
// R12: LDS-bandwidth diet. R10/R11 falsified the latency theory (2x occupancy,
//     flat time) -> the binder is the shared per-CU LDS pipe (broadcast
//     ds_read_b128 of weight constants ~= measured kernel time at 16 waves/CU).
//     Changes vs R7 (best measured, structure restored):
//     (1) ray-INDEPENDENT weights (W2, Wc2) read via uniform scalar loads
//         (s_load, scalar cache, zero LDS cycles); LN2 folded at epilogue.
//     (2) LDS slimmed to 2 ray-dependent tables: sP0{a,a',c,c'} (16B/slot
//         march) and sC{aC,aC',cC,cC'} (+16B for color).
//     (3) phase 3 = ONE packed pass: lane carries samples (lane, 64+(lane&31))
//         as f2 -> 96 samples in one 64-slot sweep, no second pass, no fold.
// Carried from R7: 1 wave/ray, early-exit chunked march (d=0 gate, half-A
//     first), in-register crossing search on logit signs, secant on register
//     reparams, dfar==0 fast path, in-register 96-sample compositing scan.
// Carried: packed-f32 math, log2-domain softplus (Estrin), f2 step packing.

namespace {

constexpr int H_    = 128;
constexpr int RS    = 128;   // RAY_STEPS
constexpr int NSEC  = 8;
constexpr int SOUT_ = 32;    // STEPS_OUT
constexpr int SIN_  = 64;    // STEPS_IN
constexpr int FULL_ = 96;
constexpr float EPSA   = 1e-6f;
constexpr float DELTA_ = 0.44626032029685964f; // max(2*exp(-1.5), 0.1)
constexpr float L2E    = 1.4426950408889634f;  // log2(e)
constexpr float LN2    = 0.6931471805599453f;

typedef __attribute__((ext_vector_type(2))) float f2;

__device__ __forceinline__ f2 s2(float v) { return f2{v, v}; }

// deg-6 poly for log2(1+e), e in [0,1], via t = 2e-1, max err ~1e-4. Estrin.
constexpr float PC0 =  0.5849625007211562f;
constexpr float PC1 =  0.4808983469629878f;
constexpr float PC2 = -0.0801497244938313f;
constexpr float PC3 =  0.0178110498875181f;
constexpr float PC4 = -0.0044527624718795f;
constexpr float PC5 =  0.0011873633258345f;
constexpr float PC6 = -0.0003298231460651f;

// packed log2-domain softplus: sp2(u) = max(u,0) + log2(1 + 2^-|u|)
__device__ __forceinline__ f2 sp2p(f2 u) {
    f2 e;
    e.x = __builtin_amdgcn_exp2f(-fabsf(u.x));
    e.y = __builtin_amdgcn_exp2f(-fabsf(u.y));
    f2 t  = e + e - 1.0f;
    f2 t2 = t * t;
    f2 t4 = t2 * t2;
    f2 A = __builtin_elementwise_fma(t, s2(PC1), s2(PC0));
    f2 B = __builtin_elementwise_fma(t, s2(PC3), s2(PC2));
    f2 C = __builtin_elementwise_fma(t, s2(PC5), s2(PC4));
    f2 E = __builtin_elementwise_fma(t2, B, A);
    f2 F = __builtin_elementwise_fma(t2, s2(PC6), C);
    f2 p = __builtin_elementwise_fma(t4, F, E);
    return __builtin_elementwise_max(u, s2(0.0f)) + p;
}

__device__ __forceinline__ float sigmoid_fast(float x) {
    return __builtin_amdgcn_rcpf(1.0f + __expf(-x));
}
__device__ __forceinline__ float sgnf(float p) {
    return (p > 0.0f) ? 1.0f : ((p < 0.0f) ? -1.0f : 0.0f);
}
__device__ __forceinline__ float secant_step(float f_l, float f_h, float d_l, float d_h) {
    float den = f_h - f_l;
    if (fabsf(den) > 1e-12f) return -f_l * (d_h - d_l) / den + d_l;
    return 0.5f * (d_l + d_h);
}
__device__ __forceinline__ float2 ld2(const float* p) {
    return *reinterpret_cast<const float2*>(p);
}

__device__ void inv4(const float* m, float* o) {
    float inv[16];
    inv[0]  =  m[5]*m[10]*m[15] - m[5]*m[11]*m[14] - m[9]*m[6]*m[15] + m[9]*m[7]*m[14] + m[13]*m[6]*m[11] - m[13]*m[7]*m[10];
    inv[4]  = -m[4]*m[10]*m[15] + m[4]*m[11]*m[14] + m[8]*m[6]*m[15] - m[8]*m[7]*m[14] - m[12]*m[6]*m[11] + m[12]*m[7]*m[10];
    inv[8]  =  m[4]*m[9]*m[15]  - m[4]*m[11]*m[13] - m[8]*m[5]*m[15] + m[8]*m[7]*m[13] + m[12]*m[5]*m[11] - m[12]*m[7]*m[9];
    inv[12] = -m[4]*m[9]*m[14]  + m[4]*m[10]*m[13] + m[8]*m[5]*m[14] - m[8]*m[6]*m[13] - m[12]*m[5]*m[10] + m[12]*m[6]*m[9];
    inv[1]  = -m[1]*m[10]*m[15] + m[1]*m[11]*m[14] + m[9]*m[2]*m[15] - m[9]*m[3]*m[14] - m[13]*m[2]*m[11] + m[13]*m[3]*m[10];
    inv[5]  =  m[0]*m[10]*m[15] - m[0]*m[11]*m[14] - m[8]*m[2]*m[15] + m[8]*m[3]*m[14] + m[12]*m[2]*m[11] - m[12]*m[3]*m[10];
    inv[9]  = -m[0]*m[9]*m[15]  + m[0]*m[11]*m[13] + m[8]*m[1]*m[15] - m[8]*m[3]*m[13] - m[12]*m[1]*m[11] + m[12]*m[3]*m[9];
    inv[13] =  m[0]*m[9]*m[14]  - m[0]*m[10]*m[13] - m[8]*m[1]*m[14] + m[8]*m[2]*m[13] + m[12]*m[1]*m[10] - m[12]*m[2]*m[9];
    inv[2]  =  m[1]*m[6]*m[15]  - m[1]*m[7]*m[14]  - m[5]*m[2]*m[15] + m[5]*m[3]*m[14] + m[13]*m[2]*m[7]  - m[13]*m[3]*m[6];
    inv[6]  = -m[0]*m[6]*m[15]  + m[0]*m[7]*m[14]  + m[4]*m[2]*m[15] - m[4]*m[3]*m[14] - m[12]*m[2]*m[7]  + m[12]*m[3]*m[6];
    inv[10] =  m[0]*m[5]*m[15]  - m[0]*m[7]*m[13]  - m[4]*m[1]*m[15] + m[4]*m[3]*m[13] + m[12]*m[1]*m[7]  - m[12]*m[3]*m[5];
    inv[14] = -m[0]*m[5]*m[14]  + m[0]*m[6]*m[13]  + m[4]*m[1]*m[14] - m[4]*m[2]*m[13] - m[12]*m[1]*m[6]  + m[12]*m[2]*m[5];
    inv[3]  = -m[1]*m[6]*m[11]  + m[1]*m[7]*m[10]  + m[5]*m[2]*m[11] - m[5]*m[3]*m[10] - m[9]*m[2]*m[7]   + m[9]*m[3]*m[6];
    inv[7]  =  m[0]*m[6]*m[11]  - m[0]*m[7]*m[10]  - m[4]*m[2]*m[11] + m[4]*m[3]*m[10] + m[8]*m[2]*m[7]   - m[8]*m[3]*m[6];
    inv[11] = -m[0]*m[5]*m[11]  + m[0]*m[7]*m[9]   + m[4]*m[1]*m[11] - m[4]*m[3]*m[9]  - m[8]*m[1]*m[7]   + m[8]*m[3]*m[5];
    inv[15] =  m[0]*m[5]*m[10]  - m[0]*m[6]*m[9]   - m[4]*m[1]*m[10] + m[4]*m[2]*m[9]  + m[8]*m[1]*m[6]   - m[8]*m[2]*m[5];
    float det = m[0]*inv[0] + m[1]*inv[4] + m[2]*inv[8] + m[3]*inv[12];
    float idet = 1.0f / det;
    for (int i = 0; i < 16; i++) o[i] = inv[i] * idet;
}

__global__ __launch_bounds__(64) void render_k(
    const float* __restrict__ pixels,
    const float* __restrict__ Cm, const float* __restrict__ Wm, const float* __restrict__ Sm,
    const float* __restrict__ W1, const float* __restrict__ b1,
    const float* __restrict__ W2, const float* __restrict__ b2,
    const float* __restrict__ Wc1, const float* __restrict__ bc1,
    const float* __restrict__ Wc2, const float* __restrict__ bc2,
    float* __restrict__ out, int N)
{
    const int lane = threadIdx.x;     // 0..63, one wave
    const int r    = blockIdx.x;      // one ray per block

    // ray-dependent reparam LDS tables (pair-major): slot j = units 2j, 2j+1
    __shared__ float4 sP0[H_/2];      // {a,a', c,c'}   occ, log2 domain
    __shared__ float4 sC [H_/2];      // {aC,aC', cC,cC'}  color
    __shared__ float  sInv[3][16];    // iC, iW, iS
    __shared__ float  sT[16], sM[16];

    // uniform-indexed views for scalar (s_load) access in hot loops
    const float2* __restrict__ W2p  = reinterpret_cast<const float2*>(W2);
    const float2* __restrict__ Wc2p = reinterpret_cast<const float2*>(Wc2);

    // ---- geometry: one inv4, matrices spread over lanes 0..2 ----
    {
        const float* mm = (lane == 0) ? Cm : ((lane == 1) ? Wm : Sm);
        float o[16];
        inv4(mm, o);                  // control-uniform; data-divergent
        if (lane < 3)
            for (int k = 0; k < 16; k++) sInv[lane][k] = o[k];
    }
    __syncthreads();
    if (lane < 16) {                  // T = iW @ iC
        int row = lane >> 2, col = lane & 3;
        float s = 0.0f;
        for (int k = 0; k < 4; k++) s += sInv[1][row*4 + k] * sInv[0][k*4 + col];
        sT[lane] = s;
    }
    __syncthreads();
    if (lane < 16) {                  // M = iS @ T
        int row = lane >> 2, col = lane & 3;
        float s = 0.0f;
        for (int k = 0; k < 4; k++) s += sInv[2][row*4 + k] * sT[k*4 + col];
        sM[lane] = s;
    }
    __syncthreads();

    float cx, cy, cz, rx, ry, rz, dfar;
    int mint;
    {
        const float px_ = pixels[2*r], py_ = pixels[2*r + 1];
        float cam[3], dir[3];
        for (int i = 0; i < 3; i++) {
            cam[i] = sM[4*i + 3];
            float pw = sM[4*i + 0]*px_ + sM[4*i + 1]*py_ + sM[4*i + 2] + sM[4*i + 3];
            dir[i] = pw - cam[i];
        }
        float nrm = sqrtf(dir[0]*dir[0] + dir[1]*dir[1] + dir[2]*dir[2]);
        rx = dir[0]/nrm; ry = dir[1]/nrm; rz = dir[2]/nrm;
        cx = cam[0]; cy = cam[1]; cz = cam[2];
        float rcd = rx*cx + ry*cy + rz*cz;
        float cc  = cx*cx + cy*cy + cz*cz;
        float under = rcd*rcd - (cc - 1.0f);      // RADIUS = 1
        mint = under > 0.0f;
        float s = sqrtf(mint ? under : 1.0f);
        dfar = mint ? fmaxf(s - rcd, 0.0f) : 0.0f;
    }

    // ---- staging (after geometry): lane owns hidden units 2*lane, 2*lane+1 ----
    const int u0 = 2 * lane;
    float a2k[2], c2k[2], w2k[2];               // occ (l0 gate, secant, fast path)
    float cCr[2], w0r[2], w1r[2], w2r[2];       // color (fast path only)
    {
        const float2 w1xv = ld2(W1 + u0);
        const float2 w1yv = ld2(W1 + H_ + u0);
        const float2 w1zv = ld2(W1 + 2*H_ + u0);
        const float2 b1v  = ld2(b1 + u0);
        const float2 w2v  = ld2(W2 + u0);
        a2k[0] = (w1xv.x*rx + w1yv.x*ry + w1zv.x*rz) * L2E;
        a2k[1] = (w1xv.y*rx + w1yv.y*ry + w1zv.y*rz) * L2E;
        c2k[0] = (w1xv.x*cx + w1yv.x*cy + w1zv.x*cz + b1v.x) * L2E;
        c2k[1] = (w1xv.y*cx + w1yv.y*cy + w1zv.y*cz + b1v.y) * L2E;
        w2k[0] = w2v.x * LN2;
        w2k[1] = w2v.y * LN2;
        const float2 q0v  = ld2(Wc1 + u0);
        const float2 q1v  = ld2(Wc1 + H_ + u0);
        const float2 q2v  = ld2(Wc1 + 2*H_ + u0);
        const float2 q3v  = ld2(Wc1 + 3*H_ + u0);
        const float2 q4v  = ld2(Wc1 + 4*H_ + u0);
        const float2 q5v  = ld2(Wc1 + 5*H_ + u0);
        const float2 bc1v = ld2(bc1 + u0);
        float aC0 = q0v.x*rx + q1v.x*ry + q2v.x*rz;
        float aC1 = q0v.y*rx + q1v.y*ry + q2v.y*rz;
        cCr[0] = q0v.x*cx + q1v.x*cy + q2v.x*cz + bc1v.x - (q3v.x*rx + q4v.x*ry + q5v.x*rz);
        cCr[1] = q0v.y*cx + q1v.y*cy + q2v.y*cz + bc1v.y - (q3v.y*rx + q4v.y*ry + q5v.y*rz);
        const float2 wc2a = ld2(Wc2 + 3*u0);      // {w0[0], w1[0]}
        const float2 wc2b = ld2(Wc2 + 3*u0 + 2);  // {w2[0], w0[1]}
        const float2 wc2c = ld2(Wc2 + 3*u0 + 4);  // {w1[1], w2[1]}
        w0r[0] = wc2a.x; w1r[0] = wc2a.y; w2r[0] = wc2b.x;
        w0r[1] = wc2b.y; w1r[1] = wc2c.x; w2r[1] = wc2c.y;
        sP0[lane] = float4{a2k[0], a2k[1], c2k[0], c2k[1]};
        sC [lane] = float4{aC0,    aC1,    cCr[0], cCr[1]};
    }
    const float b2v  = b2[0];
    const float bc20 = bc2[0], bc21 = bc2[1], bc22 = bc2[2];
    __syncthreads();

    float alpha0, r0c, g0c, b0c;      // sample lane
    float alpha1, r1c, g1c, b1c;      // sample 64 + (lane&31)

    if (dfar == 0.0f) {
        // ---- fast path: all 96 samples sit at the camera point ----
        f2 sp = sp2p(f2{c2k[0], c2k[1]});
        float part = sp.x*w2k[0] + sp.y*w2k[1];
        f2 ff = __builtin_elementwise_max(f2{cCr[0], cCr[1]}, s2(0.0f));
        float A0 = ff.x*w0r[0] + ff.y*w0r[1];
        float A1 = ff.x*w1r[0] + ff.y*w1r[1];
        float A2 = ff.x*w2r[0] + ff.y*w2r[1];
#pragma unroll
        for (int off = 32; off; off >>= 1) {
            part += __shfl_xor(part, off, 64);
            A0   += __shfl_xor(A0,   off, 64);
            A1   += __shfl_xor(A1,   off, 64);
            A2   += __shfl_xor(A2,   off, 64);
        }
        alpha0 = sigmoid_fast(part + b2v);
        r0c = sigmoid_fast(A0 + bc20);
        g0c = sigmoid_fast(A1 + bc21);
        b0c = sigmoid_fast(A2 + bc22);
        alpha1 = alpha0; r1c = r0c; g1c = g0c; b1c = b0c;
    } else {
        const float inv127 = 1.0f / (RS - 1);

        // ---- phase 1a: logit at d=0 (p = camera; decides mask_0_free) ----
        float l0;
        {
            f2 sp = sp2p(f2{c2k[0], c2k[1]});
            float part = sp.x*w2k[0] + sp.y*w2k[1];
#pragma unroll
            for (int off = 32; off; off >>= 1) part += __shfl_xor(part, off, 64);
            l0 = part + b2v;
        }

        float d_i;
        if (l0 >= 0.0f) {
            // mask_0_free false -> d_i = 0, background sampling; skip march.
            d_i = 0.0f;
        } else {
            // occ logit at distance dsmp: LDS = 1 b128/slot; W2 via scalar load
            auto march_logit = [&](float dsmp) -> float {
                const f2 dd = s2(dsmp);
                f2 acc = s2(0.0f);
#pragma unroll 4
                for (int j = 0; j < H_/2; ++j) {
                    float4 q0 = sP0[j];
                    float2 wv = W2p[j];           // uniform -> s_load
                    f2 u = __builtin_elementwise_fma(f2{q0.x, q0.y}, dd, f2{q0.z, q0.w});
                    acc = __builtin_elementwise_fma(sp2p(u), f2{wv.x, wv.y}, acc);
                }
                return LN2 * (acc.x + acc.y) + b2v;
            };

            // ---- phase 1b: steps 0..63, one per lane; crossing on logit sign ----
            float lA = march_logit(dfar * ((float)lane * inv127));
            float lan = __shfl_down(lA, 1, 64);
            float ca = (lane < 63) ? sgnf(lA * lan) * (float)(RS - lane) : 1.0f;
            float cmin = ca; int ind = lane;
#pragma unroll
            for (int off = 32; off; off >>= 1) {
                float c2 = __shfl_xor(cmin, off, 64);
                int   i2 = __shfl_xor(ind,  off, 64);
                if (c2 < cmin || (c2 == cmin && i2 < ind)) { cmin = c2; ind = i2; }
            }
            int crossed = cmin < 0.0f;            // wave-uniform
            float ll = 0.0f, lh = 0.0f;           // bracket logits
            if (crossed) {
                ll = __shfl(lA, ind, 64);
                lh = __shfl(lA, ind + 1, 64);
            } else {
                // ---- phase 1c: steps 64..127 (only when half A is clean) ----
                float lB = march_logit(dfar * ((float)(lane + 64) * inv127));
                float l63 = __shfl(lA, 63, 64);
                float l64 = __shfl(lB, 0, 64);
                if (l63 * l64 < 0.0f) {           // boundary pair (63,64)
                    crossed = 1; ind = 63;
                    ll = l63; lh = l64;
                } else {
                    float lbn = __shfl_down(lB, 1, 64);
                    float cb = (lane < 63) ? sgnf(lB * lbn) * (float)(64 - lane) : 1.0f;
                    float cminb = cb; int indl = lane;
#pragma unroll
                    for (int off = 32; off; off >>= 1) {
                        float c2 = __shfl_xor(cminb, off, 64);
                        int   i2 = __shfl_xor(indl,  off, 64);
                        if (c2 < cminb || (c2 == cminb && i2 < indl)) { cminb = c2; indl = i2; }
                    }
                    if (cminb < 0.0f) {
                        crossed = 1; ind = 64 + indl;
                        ll = __shfl(lB, indl, 64);
                        lh = __shfl(lB, indl + 1, 64);
                    }
                }
            }

            const int msk = crossed && (ll < 0.0f) && mint;
            if (msk) {   // wave-uniform secant refinement (register reparams)
                float f_l = sigmoid_fast(ll) - 0.5f;
                float f_h = sigmoid_fast(lh) - 0.5f;
                float d_l = dfar * ((float)ind * inv127);
                float d_h = dfar * ((float)(ind + 1) * inv127);
                float d_p = secant_step(f_l, f_h, d_l, d_h);
                for (int it = 0; it < NSEC; it++) {
                    f2 u2 = __builtin_elementwise_fma(f2{a2k[0], a2k[1]}, s2(d_p),
                                                      f2{c2k[0], c2k[1]});
                    f2 sp = sp2p(u2);
                    float part = sp.x*w2k[0] + sp.y*w2k[1];
#pragma unroll
                    for (int off = 32; off; off >>= 1) part += __shfl_xor(part, off, 64);
                    float fm = sigmoid_fast(part + b2v) - 0.5f;
                    bool low = fm < 0.0f;
                    d_l = low ? d_p : d_l;  f_l = low ? fm : f_l;
                    d_h = low ? d_h : d_p;  f_h = low ? f_h : fm;
                    d_p = secant_step(f_l, f_h, d_l, d_h);
                }
                d_i = d_p;
            } else {
                d_i = INFINITY;
            }
        }

        // ---- depth interval selection (matches reference d_i plumbing) ----
        const int mask_zero = (d_i == 0.0f);
        const int mask_pred = isfinite(d_i);
        float dists = mask_pred ? d_i : 1.0f;
        if (mask_zero) dists = 0.0f;
        const int obj = mask_pred && !mask_zero;
        const float dnp = fmaxf(dists - DELTA_, 0.0f);
        const float dfp = fminf(dists + DELTA_, dfar);

        auto sample_d = [&](int s) -> float {
            if (obj) {
                if (s < SOUT_) return dnp * ((float)s * (1.0f / (SOUT_ - 1)));
                float u = (float)(s - SOUT_) * (1.0f / (SIN_ - 1));
                return dnp * (1.0f - u) + dfp * u;
            }
            return dfar * ((float)s * (1.0f / (FULL_ - 1)));
        };

        // ---- phase 3: ONE packed pass; lane = samples (lane, 64+(lane&31)) ----
        {
            const f2 dd = f2{sample_d(lane), sample_d(64 + (lane & 31))};
            f2 SO = s2(0.0f), A0 = s2(0.0f), A1 = s2(0.0f), A2 = s2(0.0f);
#pragma unroll 4
            for (int j = 0; j < H_/2; ++j) {
                float4 q = sP0[j];
                float4 c = sC[j];
                float2 wv = W2p[j];               // uniform -> s_load
                float2 wa = Wc2p[3*j];            // {w0,w1} unit 2j
                float2 wb = Wc2p[3*j + 1];        // {w2 u2j, w0 u2j+1}
                float2 wc = Wc2p[3*j + 2];        // {w1,w2} unit 2j+1
                // unit 2j
                f2 u0f = __builtin_elementwise_fma(s2(q.x), dd, s2(q.z));
                SO = __builtin_elementwise_fma(sp2p(u0f), s2(wv.x), SO);
                f2 f0 = __builtin_elementwise_max(
                            __builtin_elementwise_fma(s2(c.x), dd, s2(c.z)), s2(0.0f));
                A0 = __builtin_elementwise_fma(f0, s2(wa.x), A0);
                A1 = __builtin_elementwise_fma(f0, s2(wa.y), A1);
                A2 = __builtin_elementwise_fma(f0, s2(wb.x), A2);
                // unit 2j+1
                f2 u1f = __builtin_elementwise_fma(s2(q.y), dd, s2(q.w));
                SO = __builtin_elementwise_fma(sp2p(u1f), s2(wv.y), SO);
                f2 f1 = __builtin_elementwise_max(
                            __builtin_elementwise_fma(s2(c.y), dd, s2(c.w)), s2(0.0f));
                A0 = __builtin_elementwise_fma(f1, s2(wb.y), A0);
                A1 = __builtin_elementwise_fma(f1, s2(wc.x), A1);
                A2 = __builtin_elementwise_fma(f1, s2(wc.y), A2);
            }
            alpha0 = sigmoid_fast(LN2 * SO.x + b2v);
            r0c = sigmoid_fast(A0.x + bc20);
            g0c = sigmoid_fast(A1.x + bc21);
            b0c = sigmoid_fast(A2.x + bc22);
            alpha1 = sigmoid_fast(LN2 * SO.y + b2v);
            r1c = sigmoid_fast(A0.y + bc20);
            g1c = sigmoid_fast(A1.y + bc21);
            b1c = sigmoid_fast(A2.y + bc22);
        }
    }

    // ---- compositing: in-register wave scan over 96 ordered samples ----
    {
        float mA = 1.0f - alpha0 + EPSA;
        float p = mA;
#pragma unroll
        for (int off = 1; off < 64; off <<= 1) {
            float v = __shfl_up(p, off, 64);
            if (lane >= off) p *= v;
        }
        float TexA = __shfl_up(p, 1, 64);
        if (lane == 0) TexA = 1.0f;
        float TA = __shfl(p, 63, 64);
        float wA = alpha0 * TexA;

        float mB = (lane < 32) ? (1.0f - alpha1 + EPSA) : 1.0f;
        float pb = mB;
#pragma unroll
        for (int off = 1; off < 32; off <<= 1) {
            float v = __shfl_up(pb, off, 64);
            if (lane >= off) pb *= v;
        }
        float TexB = __shfl_up(pb, 1, 64);
        if (lane == 0) TexB = 1.0f;
        float wB = (lane < 32) ? alpha1 * TexB * TA : 0.0f;

        float s0 = wA*r0c + wB*r1c;
        float s1 = wA*g0c + wB*g1c;
        float s2v = wA*b0c + wB*b1c;
#pragma unroll
        for (int off = 32; off; off >>= 1) {
            s0  += __shfl_xor(s0,  off, 64);
            s1  += __shfl_xor(s1,  off, 64);
            s2v += __shfl_xor(s2v, off, 64);
        }
        if (lane == 0) {
            out[3*r + 0] = s0;
            out[3*r + 1] = s1;
            out[3*r + 2] = s2v;
        }
    }
}

} // namespace

extern "C" void kernel_launch(void* const* d_in, const int* in_sizes, int n_in,
                              void* d_out, int out_size, void* d_ws, size_t ws_size,
                              hipStream_t stream) {
    const float* pixels = (const float*)d_in[0];
    const float* Cm  = (const float*)d_in[1];
    const float* Wm  = (const float*)d_in[2];
    const float* Sm  = (const float*)d_in[3];
    const float* W1  = (const float*)d_in[4];
    const float* b1  = (const float*)d_in[5];
    const float* W2  = (const float*)d_in[6];
    const float* b2  = (const float*)d_in[7];
    const float* Wc1 = (const float*)d_in[8];
    const float* bc1 = (const float*)d_in[9];
    const float* Wc2 = (const float*)d_in[10];
    const float* bc2 = (const float*)d_in[11];
    float* out = (float*)d_out;

    const int N = in_sizes[0] / 2;   // pixels is (B=1, N, 2)
    hipLaunchKernelGGL(render_k, dim3(N), dim3(64), 0, stream,
                       pixels, Cm, Wm, Sm, W1, b1, W2, b2, Wc1, bc1, Wc2, bc2, out, N);
}

// Round 7
// 97.215 us; speedup vs baseline: 1.1430x; 1.0760x over previous
//
#include <hip/hip_runtime.h>
#include <math.h>

// Renderer: occupancy-field ray marching + secant + shading.
// R13: R7 structure (best measured: 98.6 bench / ~33.5 us kernel) + exact
//     hardware-log softplus. sp2p was ~16 instr with a 6-deep poly chain;
//     log2(1+e) for e=2^-|u| in (0,1] is directly v_log_f32(1+e):
//     2 exp2 + pk_add + 2 log2 + pk_max + pk_add = 7 instr, depth 4,
//     and MORE accurate (~1e-7 vs 1e-4). Applied to l0, march, secant,
//     phase 3, fast path. Crossing search on raw logit signs (sigmoid
//     monotone; sigmoid only at the bracket pair). All R9-R12 machinery
//     reverted (prefetch, 2-wave split, scalar-load diet, phase-3 repack
//     all measured flat-to-negative).
// Evidence note: R6->R7 delta implies l0>=0 for ~all rays (march skipped),
//     so phase-3 + prologue dominate; sp2p is the largest instr consumer.

namespace {

constexpr int H_    = 128;
constexpr int RS    = 128;   // RAY_STEPS
constexpr int NSEC  = 8;
constexpr int SOUT_ = 32;    // STEPS_OUT
constexpr int SIN_  = 64;    // STEPS_IN
constexpr int FULL_ = 96;
constexpr float EPSA   = 1e-6f;
constexpr float DELTA_ = 0.44626032029685964f; // max(2*exp(-1.5), 0.1)
constexpr float L2E    = 1.4426950408889634f;  // log2(e)
constexpr float LN2    = 0.6931471805599453f;

typedef __attribute__((ext_vector_type(2))) float f2;

__device__ __forceinline__ f2 s2(float v) { return f2{v, v}; }

// packed log2-domain softplus: sp2(u) = max(u,0) + log2(1 + 2^-|u|)
// exact: e = 2^-|u| in (0,1], 1+e in (1,2], v_log_f32 is ~1ulp there.
__device__ __forceinline__ f2 sp2p(f2 u) {
    f2 e;
    e.x = __builtin_amdgcn_exp2f(-fabsf(u.x));
    e.y = __builtin_amdgcn_exp2f(-fabsf(u.y));
    f2 onep = e + 1.0f;
    f2 l;
    l.x = __builtin_amdgcn_logf(onep.x);   // v_log_f32 = log2
    l.y = __builtin_amdgcn_logf(onep.y);
    return __builtin_elementwise_max(u, s2(0.0f)) + l;
}

__device__ __forceinline__ float sigmoid_fast(float x) {
    return __builtin_amdgcn_rcpf(1.0f + __expf(-x));
}
__device__ __forceinline__ float sgnf(float p) {
    return (p > 0.0f) ? 1.0f : ((p < 0.0f) ? -1.0f : 0.0f);
}
__device__ __forceinline__ float secant_step(float f_l, float f_h, float d_l, float d_h) {
    float den = f_h - f_l;
    if (fabsf(den) > 1e-12f) return -f_l * (d_h - d_l) / den + d_l;
    return 0.5f * (d_l + d_h);
}
__device__ __forceinline__ float2 ld2(const float* p) {
    return *reinterpret_cast<const float2*>(p);
}

__device__ void inv4(const float* m, float* o) {
    float inv[16];
    inv[0]  =  m[5]*m[10]*m[15] - m[5]*m[11]*m[14] - m[9]*m[6]*m[15] + m[9]*m[7]*m[14] + m[13]*m[6]*m[11] - m[13]*m[7]*m[10];
    inv[4]  = -m[4]*m[10]*m[15] + m[4]*m[11]*m[14] + m[8]*m[6]*m[15] - m[8]*m[7]*m[14] - m[12]*m[6]*m[11] + m[12]*m[7]*m[10];
    inv[8]  =  m[4]*m[9]*m[15]  - m[4]*m[11]*m[13] - m[8]*m[5]*m[15] + m[8]*m[7]*m[13] + m[12]*m[5]*m[11] - m[12]*m[7]*m[9];
    inv[12] = -m[4]*m[9]*m[14]  + m[4]*m[10]*m[13] + m[8]*m[5]*m[14] - m[8]*m[6]*m[13] - m[12]*m[5]*m[10] + m[12]*m[6]*m[9];
    inv[1]  = -m[1]*m[10]*m[15] + m[1]*m[11]*m[14] + m[9]*m[2]*m[15] - m[9]*m[3]*m[14] - m[13]*m[2]*m[11] + m[13]*m[3]*m[10];
    inv[5]  =  m[0]*m[10]*m[15] - m[0]*m[11]*m[14] - m[8]*m[2]*m[15] + m[8]*m[3]*m[14] + m[12]*m[2]*m[11] - m[12]*m[3]*m[10];
    inv[9]  = -m[0]*m[9]*m[15]  + m[0]*m[11]*m[13] + m[8]*m[1]*m[15] - m[8]*m[3]*m[13] - m[12]*m[1]*m[11] + m[12]*m[3]*m[9];
    inv[13] =  m[0]*m[9]*m[14]  - m[0]*m[10]*m[13] - m[8]*m[1]*m[14] + m[8]*m[2]*m[13] + m[12]*m[1]*m[10] - m[12]*m[2]*m[9];
    inv[2]  =  m[1]*m[6]*m[15]  - m[1]*m[7]*m[14]  - m[5]*m[2]*m[15] + m[5]*m[3]*m[14] + m[13]*m[2]*m[7]  - m[13]*m[3]*m[6];
    inv[6]  = -m[0]*m[6]*m[15]  + m[0]*m[7]*m[14]  + m[4]*m[2]*m[15] - m[4]*m[3]*m[14] - m[12]*m[2]*m[7]  + m[12]*m[3]*m[6];
    inv[10] =  m[0]*m[5]*m[15]  - m[0]*m[7]*m[13]  - m[4]*m[1]*m[15] + m[4]*m[3]*m[13] + m[12]*m[1]*m[7]  - m[12]*m[3]*m[5];
    inv[14] = -m[0]*m[5]*m[14]  + m[0]*m[6]*m[13]  + m[4]*m[1]*m[14] - m[4]*m[2]*m[13] - m[12]*m[1]*m[6]  + m[12]*m[2]*m[5];
    inv[3]  = -m[1]*m[6]*m[11]  + m[1]*m[7]*m[10]  + m[5]*m[2]*m[11] - m[5]*m[3]*m[10] - m[9]*m[2]*m[7]   + m[9]*m[3]*m[6];
    inv[7]  =  m[0]*m[6]*m[11]  - m[0]*m[7]*m[10]  - m[4]*m[2]*m[11] + m[4]*m[3]*m[10] + m[8]*m[2]*m[7]   - m[8]*m[3]*m[6];
    inv[11] = -m[0]*m[5]*m[11]  + m[0]*m[7]*m[9]   + m[4]*m[1]*m[11] - m[4]*m[3]*m[9]  - m[8]*m[1]*m[7]   + m[8]*m[3]*m[5];
    inv[15] =  m[0]*m[5]*m[10]  - m[0]*m[6]*m[9]   - m[4]*m[1]*m[10] + m[4]*m[2]*m[9]  + m[8]*m[1]*m[6]   - m[8]*m[2]*m[5];
    float det = m[0]*inv[0] + m[1]*inv[4] + m[2]*inv[8] + m[3]*inv[12];
    float idet = 1.0f / det;
    for (int i = 0; i < 16; i++) o[i] = inv[i] * idet;
}

__global__ __launch_bounds__(64) void render_k(
    const float* __restrict__ pixels,
    const float* __restrict__ Cm, const float* __restrict__ Wm, const float* __restrict__ Sm,
    const float* __restrict__ W1, const float* __restrict__ b1,
    const float* __restrict__ W2, const float* __restrict__ b2,
    const float* __restrict__ Wc1, const float* __restrict__ bc1,
    const float* __restrict__ Wc2, const float* __restrict__ bc2,
    float* __restrict__ out, int N)
{
    const int tid = threadIdx.x;      // 0..63, one wave
    const int r   = blockIdx.x;       // one ray per block

    // pair-major weight LDS: slot j2 holds hidden units 2*j2, 2*j2+1
    __shared__ float4 sP0[H_/2];      // {a,a', c,c'}       (occ, log2 domain)
    __shared__ float4 sP1[H_/2];      // {w,w', aC,aC'}     (w = w2*ln2)
    __shared__ float4 sP2[H_/2];      // {cC,cC', w0,w0'}
    __shared__ float4 sP3[H_/2];      // {w1,w1', w2,w2'}
    __shared__ f2     sW2[H_/2];      // {w,w'}  (occ-only marching loop)
    __shared__ float  sInv[3][16];    // iC, iW, iS
    __shared__ float  sT[16], sM[16];

    // ---- geometry: one inv4, matrices spread over lanes 0..2 ----
    {
        const float* mm = (tid == 0) ? Cm : ((tid == 1) ? Wm : Sm);
        float o[16];
        inv4(mm, o);                  // control-uniform; data-divergent
        if (tid < 3)
            for (int k = 0; k < 16; k++) sInv[tid][k] = o[k];
    }
    __syncthreads();
    if (tid < 16) {                   // T = iW @ iC
        int row = tid >> 2, col = tid & 3;
        float s = 0.0f;
        for (int k = 0; k < 4; k++) s += sInv[1][row*4 + k] * sInv[0][k*4 + col];
        sT[tid] = s;
    }
    __syncthreads();
    if (tid < 16) {                   // M = iS @ T
        int row = tid >> 2, col = tid & 3;
        float s = 0.0f;
        for (int k = 0; k < 4; k++) s += sInv[2][row*4 + k] * sT[k*4 + col];
        sM[tid] = s;
    }
    __syncthreads();

    float cx, cy, cz, rx, ry, rz, dfar;
    int mint;
    {
        const float px_ = pixels[2*r], py_ = pixels[2*r + 1];
        float cam[3], dir[3];
        for (int i = 0; i < 3; i++) {
            cam[i] = sM[4*i + 3];
            float pw = sM[4*i + 0]*px_ + sM[4*i + 1]*py_ + sM[4*i + 2] + sM[4*i + 3];
            dir[i] = pw - cam[i];
        }
        float nrm = sqrtf(dir[0]*dir[0] + dir[1]*dir[1] + dir[2]*dir[2]);
        rx = dir[0]/nrm; ry = dir[1]/nrm; rz = dir[2]/nrm;
        cx = cam[0]; cy = cam[1]; cz = cam[2];
        float rcd = rx*cx + ry*cy + rz*cz;
        float cc  = cx*cx + cy*cy + cz*cz;
        float under = rcd*rcd - (cc - 1.0f);      // RADIUS = 1
        mint = under > 0.0f;
        float s = sqrtf(mint ? under : 1.0f);
        dfar = mint ? fmaxf(s - rcd, 0.0f) : 0.0f;
    }

    // ---- staging + reparam: lane stages hidden units 2*tid, 2*tid+1 ----
    float a2k[2], c2k[2], w2k[2];               // occ (secant + fast path)
    float cCr[2], w0r[2], w1r[2], w2r[2];       // color (fast path)
    {
        const int u0 = 2 * tid;
        const float2 w1xv = ld2(W1 + u0);
        const float2 w1yv = ld2(W1 + H_ + u0);
        const float2 w1zv = ld2(W1 + 2*H_ + u0);
        const float2 b1v  = ld2(b1 + u0);
        const float2 w2v  = ld2(W2 + u0);
        a2k[0] = (w1xv.x*rx + w1yv.x*ry + w1zv.x*rz) * L2E;
        a2k[1] = (w1xv.y*rx + w1yv.y*ry + w1zv.y*rz) * L2E;
        c2k[0] = (w1xv.x*cx + w1yv.x*cy + w1zv.x*cz + b1v.x) * L2E;
        c2k[1] = (w1xv.y*cx + w1yv.y*cy + w1zv.y*cz + b1v.y) * L2E;
        w2k[0] = w2v.x * LN2;
        w2k[1] = w2v.y * LN2;
        const float2 q0v  = ld2(Wc1 + u0);
        const float2 q1v  = ld2(Wc1 + H_ + u0);
        const float2 q2v  = ld2(Wc1 + 2*H_ + u0);
        const float2 q3v  = ld2(Wc1 + 3*H_ + u0);
        const float2 q4v  = ld2(Wc1 + 4*H_ + u0);
        const float2 q5v  = ld2(Wc1 + 5*H_ + u0);
        const float2 bc1v = ld2(bc1 + u0);
        float aC0 = q0v.x*rx + q1v.x*ry + q2v.x*rz;
        float aC1 = q0v.y*rx + q1v.y*ry + q2v.y*rz;
        cCr[0] = q0v.x*cx + q1v.x*cy + q2v.x*cz + bc1v.x - (q3v.x*rx + q4v.x*ry + q5v.x*rz);
        cCr[1] = q0v.y*cx + q1v.y*cy + q2v.y*cz + bc1v.y - (q3v.y*rx + q4v.y*ry + q5v.y*rz);
        const float2 wc2a = ld2(Wc2 + 3*u0);      // {w0[0], w1[0]}
        const float2 wc2b = ld2(Wc2 + 3*u0 + 2);  // {w2[0], w0[1]}
        const float2 wc2c = ld2(Wc2 + 3*u0 + 4);  // {w1[1], w2[1]}
        w0r[0] = wc2a.x; w1r[0] = wc2a.y; w2r[0] = wc2b.x;
        w0r[1] = wc2b.y; w1r[1] = wc2c.x; w2r[1] = wc2c.y;
        sP0[tid] = float4{a2k[0], a2k[1], c2k[0], c2k[1]};
        sP1[tid] = float4{w2k[0], w2k[1], aC0, aC1};
        sP2[tid] = float4{cCr[0], cCr[1], w0r[0], w0r[1]};
        sP3[tid] = float4{w1r[0], w1r[1], w2r[0], w2r[1]};
        sW2[tid] = f2{w2k[0], w2k[1]};
    }
    const float b2v  = b2[0];
    const float bc20 = bc2[0], bc21 = bc2[1], bc22 = bc2[2];
    __syncthreads();

    float alpha0, r0c, g0c, b0c;      // sample tid
    float alpha1, r1c, g1c, b1c;      // sample 64 + (tid&31)

    if (dfar == 0.0f) {
        // ---- fast path: all 96 samples sit at the camera point ----
        f2 sp = sp2p(f2{c2k[0], c2k[1]});
        float part = sp.x*w2k[0] + sp.y*w2k[1];
        f2 ff = __builtin_elementwise_max(f2{cCr[0], cCr[1]}, s2(0.0f));
        float A0 = ff.x*w0r[0] + ff.y*w0r[1];
        float A1 = ff.x*w1r[0] + ff.y*w1r[1];
        float A2 = ff.x*w2r[0] + ff.y*w2r[1];
#pragma unroll
        for (int off = 32; off; off >>= 1) {
            part += __shfl_xor(part, off, 64);
            A0   += __shfl_xor(A0,   off, 64);
            A1   += __shfl_xor(A1,   off, 64);
            A2   += __shfl_xor(A2,   off, 64);
        }
        alpha0 = sigmoid_fast(part + b2v);
        r0c = sigmoid_fast(A0 + bc20);
        g0c = sigmoid_fast(A1 + bc21);
        b0c = sigmoid_fast(A2 + bc22);
        alpha1 = alpha0; r1c = r0c; g1c = g0c; b1c = b0c;
    } else {
        const float inv127 = 1.0f / (RS - 1);

        // ---- phase 1a: logit at d=0 (p = camera; decides mask_0_free) ----
        float l0;
        {
            f2 sp = sp2p(f2{c2k[0], c2k[1]});
            float part = sp.x*w2k[0] + sp.y*w2k[1];
#pragma unroll
            for (int off = 32; off; off >>= 1) part += __shfl_xor(part, off, 64);
            l0 = part + b2v;
        }

        float d_i;
        if (l0 >= 0.0f) {
            // mask_0_free false -> d_i = 0, background sampling; skip march.
            d_i = 0.0f;
        } else {
            // occ-only MLP logit at distance dsmp (hidden-unit-pair packing)
            auto march_logit = [&](float dsmp) -> float {
                const f2 dd = s2(dsmp);
                f2 acc = s2(0.0f);
#pragma unroll 4
                for (int j2 = 0; j2 < H_/2; j2++) {
                    float4 q0 = sP0[j2];
                    f2 wv = sW2[j2];
                    f2 u = __builtin_elementwise_fma(f2{q0.x, q0.y}, dd, f2{q0.z, q0.w});
                    acc = __builtin_elementwise_fma(sp2p(u), wv, acc);
                }
                return acc.x + acc.y + b2v;
            };

            // ---- phase 1b: steps 0..63, one per lane; crossing on logit sign ----
            float lA = march_logit(dfar * ((float)tid * inv127));
            float lan = __shfl_down(lA, 1, 64);
            float ca = (tid < 63) ? sgnf(lA * lan) * (float)(RS - tid) : 1.0f;
            float cmin = ca; int ind = tid;
#pragma unroll
            for (int off = 32; off; off >>= 1) {
                float c2 = __shfl_xor(cmin, off, 64);
                int   i2 = __shfl_xor(ind,  off, 64);
                if (c2 < cmin || (c2 == cmin && i2 < ind)) { cmin = c2; ind = i2; }
            }
            int crossed = cmin < 0.0f;            // wave-uniform
            float ll = 0.0f, lh = 0.0f;           // bracket logits
            if (crossed) {
                ll = __shfl(lA, ind, 64);
                lh = __shfl(lA, ind + 1, 64);
            } else {
                // ---- phase 1c: steps 64..127 (only when half A is clean) ----
                float lB = march_logit(dfar * ((float)(tid + 64) * inv127));
                float l63 = __shfl(lA, 63, 64);
                float l64 = __shfl(lB, 0, 64);
                if (l63 * l64 < 0.0f) {           // boundary pair (63,64)
                    crossed = 1; ind = 63;
                    ll = l63; lh = l64;
                } else {
                    float lbn = __shfl_down(lB, 1, 64);
                    float cb = (tid < 63) ? sgnf(lB * lbn) * (float)(64 - tid) : 1.0f;
                    float cminb = cb; int indl = tid;
#pragma unroll
                    for (int off = 32; off; off >>= 1) {
                        float c2 = __shfl_xor(cminb, off, 64);
                        int   i2 = __shfl_xor(indl,  off, 64);
                        if (c2 < cminb || (c2 == cminb && i2 < indl)) { cminb = c2; indl = i2; }
                    }
                    if (cminb < 0.0f) {
                        crossed = 1; ind = 64 + indl;
                        ll = __shfl(lB, indl, 64);
                        lh = __shfl(lB, indl + 1, 64);
                    }
                }
            }

            const int msk = crossed && (ll < 0.0f) && mint;
            if (msk) {   // wave-uniform secant refinement
                float f_l = sigmoid_fast(ll) - 0.5f;
                float f_h = sigmoid_fast(lh) - 0.5f;
                float d_l = dfar * ((float)ind * inv127);
                float d_h = dfar * ((float)(ind + 1) * inv127);
                float d_p = secant_step(f_l, f_h, d_l, d_h);
                for (int it = 0; it < NSEC; it++) {
                    f2 u2 = __builtin_elementwise_fma(f2{a2k[0], a2k[1]}, s2(d_p),
                                                      f2{c2k[0], c2k[1]});
                    f2 sp = sp2p(u2);
                    float part = sp.x*w2k[0] + sp.y*w2k[1];
#pragma unroll
                    for (int off = 32; off; off >>= 1) part += __shfl_xor(part, off, 64);
                    float fm = sigmoid_fast(part + b2v) - 0.5f;
                    bool low = fm < 0.0f;
                    d_l = low ? d_p : d_l;  f_l = low ? fm : f_l;
                    d_h = low ? d_h : d_p;  f_h = low ? f_h : fm;
                    d_p = secant_step(f_l, f_h, d_l, d_h);
                }
                d_i = d_p;
            } else {
                d_i = INFINITY;
            }
        }

        // ---- depth interval selection (matches reference d_i plumbing) ----
        const int mask_zero = (d_i == 0.0f);
        const int mask_pred = isfinite(d_i);
        float dists = mask_pred ? d_i : 1.0f;
        if (mask_zero) dists = 0.0f;
        const int obj = mask_pred && !mask_zero;
        const float dnp = fmaxf(dists - DELTA_, 0.0f);
        const float dfp = fminf(dists + DELTA_, dfar);

        auto sample_d = [&](int s) -> float {
            if (obj) {
                if (s < SOUT_) return dnp * ((float)s * (1.0f / (SOUT_ - 1)));
                float u = (float)(s - SOUT_) * (1.0f / (SIN_ - 1));
                return dnp * (1.0f - u) + dfp * u;
            }
            return dfar * ((float)s * (1.0f / (FULL_ - 1)));
        };

        // ---- phase 3, pass 0: samples 0..63, hidden units paired ----
        {
            const f2 dd = s2(sample_d(tid));
            f2 SO = s2(0.0f), A0 = s2(0.0f), A1 = s2(0.0f), A2 = s2(0.0f);
#pragma unroll 4
            for (int j2 = 0; j2 < H_/2; j2++) {
                float4 q0 = sP0[j2];
                float4 q1 = sP1[j2];
                float4 q2 = sP2[j2];
                float4 q3 = sP3[j2];
                f2 u = __builtin_elementwise_fma(f2{q0.x, q0.y}, dd, f2{q0.z, q0.w});
                SO = __builtin_elementwise_fma(sp2p(u), f2{q1.x, q1.y}, SO);
                f2 f = __builtin_elementwise_max(
                           __builtin_elementwise_fma(f2{q1.z, q1.w}, dd, f2{q2.x, q2.y}),
                           s2(0.0f));
                A0 = __builtin_elementwise_fma(f, f2{q2.z, q2.w}, A0);
                A1 = __builtin_elementwise_fma(f, f2{q3.x, q3.y}, A1);
                A2 = __builtin_elementwise_fma(f, f2{q3.z, q3.w}, A2);
            }
            alpha0 = sigmoid_fast(SO.x + SO.y + b2v);
            r0c = sigmoid_fast(A0.x + A0.y + bc20);
            g0c = sigmoid_fast(A1.x + A1.y + bc21);
            b0c = sigmoid_fast(A2.x + A2.y + bc22);
        }

        // ---- phase 3, pass 1: samples 64..95; pair-range split by half-wave ----
        {
            const int s1 = 64 + (tid & 31);
            const int jb = (tid >> 5) * (H_/4);   // 0 or 32 pair-slots
            const f2 dd = s2(sample_d(s1));
            f2 SO = s2(0.0f), A0 = s2(0.0f), A1 = s2(0.0f), A2 = s2(0.0f);
#pragma unroll 4
            for (int j2 = jb; j2 < jb + H_/4; j2++) {
                float4 q0 = sP0[j2];
                float4 q1 = sP1[j2];
                float4 q2 = sP2[j2];
                float4 q3 = sP3[j2];
                f2 u = __builtin_elementwise_fma(f2{q0.x, q0.y}, dd, f2{q0.z, q0.w});
                SO = __builtin_elementwise_fma(sp2p(u), f2{q1.x, q1.y}, SO);
                f2 f = __builtin_elementwise_max(
                           __builtin_elementwise_fma(f2{q1.z, q1.w}, dd, f2{q2.x, q2.y}),
                           s2(0.0f));
                A0 = __builtin_elementwise_fma(f, f2{q2.z, q2.w}, A0);
                A1 = __builtin_elementwise_fma(f, f2{q3.x, q3.y}, A1);
                A2 = __builtin_elementwise_fma(f, f2{q3.z, q3.w}, A2);
            }
            float SOs = SO.x + SO.y, A0s = A0.x + A0.y;
            float A1s = A1.x + A1.y, A2s = A2.x + A2.y;
            SOs += __shfl_xor(SOs, 32, 64);
            A0s += __shfl_xor(A0s, 32, 64);
            A1s += __shfl_xor(A1s, 32, 64);
            A2s += __shfl_xor(A2s, 32, 64);
            alpha1 = sigmoid_fast(SOs + b2v);
            r1c = sigmoid_fast(A0s + bc20);
            g1c = sigmoid_fast(A1s + bc21);
            b1c = sigmoid_fast(A2s + bc22);
        }
    }

    // ---- compositing: in-register wave scan over 96 ordered samples ----
    {
        float mA = 1.0f - alpha0 + EPSA;
        float p = mA;
#pragma unroll
        for (int off = 1; off < 64; off <<= 1) {
            float v = __shfl_up(p, off, 64);
            if (tid >= off) p *= v;
        }
        float TexA = __shfl_up(p, 1, 64);
        if (tid == 0) TexA = 1.0f;
        float TA = __shfl(p, 63, 64);
        float wA = alpha0 * TexA;

        float mB = (tid < 32) ? (1.0f - alpha1 + EPSA) : 1.0f;
        float pb = mB;
#pragma unroll
        for (int off = 1; off < 32; off <<= 1) {
            float v = __shfl_up(pb, off, 64);
            if (tid >= off) pb *= v;
        }
        float TexB = __shfl_up(pb, 1, 64);
        if (tid == 0) TexB = 1.0f;
        float wB = (tid < 32) ? alpha1 * TexB * TA : 0.0f;

        float s0 = wA*r0c + wB*r1c;
        float s1 = wA*g0c + wB*g1c;
        float s2v = wA*b0c + wB*b1c;
#pragma unroll
        for (int off = 32; off; off >>= 1) {
            s0  += __shfl_xor(s0,  off, 64);
            s1  += __shfl_xor(s1,  off, 64);
            s2v += __shfl_xor(s2v, off, 64);
        }
        if (tid == 0) {
            out[3*r + 0] = s0;
            out[3*r + 1] = s1;
            out[3*r + 2] = s2v;
        }
    }
}

} // namespace

extern "C" void kernel_launch(void* const* d_in, const int* in_sizes, int n_in,
                              void* d_out, int out_size, void* d_ws, size_t ws_size,
                              hipStream_t stream) {
    const float* pixels = (const float*)d_in[0];
    const float* Cm  = (const float*)d_in[1];
    const float* Wm  = (const float*)d_in[2];
    const float* Sm  = (const float*)d_in[3];
    const float* W1  = (const float*)d_in[4];
    const float* b1  = (const float*)d_in[5];
    const float* W2  = (const float*)d_in[6];
    const float* b2  = (const float*)d_in[7];
    const float* Wc1 = (const float*)d_in[8];
    const float* bc1 = (const float*)d_in[9];
    const float* Wc2 = (const float*)d_in[10];
    const float* bc2 = (const float*)d_in[11];
    float* out = (float*)d_out;

    const int N = in_sizes[0] / 2;   // pixels is (B=1, N, 2)
    hipLaunchKernelGGL(render_k, dim3(N), dim3(64), 0, stream,
                       pixels, Cm, Wm, Sm, W1, b1, W2, b2, Wc1, bc1, Wc2, bc2, out, N);
}